// Round 1
// baseline (215.755 us; speedup 1.0000x reference)
//
#include <hip/hip_runtime.h>

#ifndef M_PIf
#define M_PIf 3.14159265358979323846f
#endif

constexpr int NNODE = 4000;
constexpr int NEDGE = 48000;
constexpr int NLA   = 20;                 // angular terms
constexpr int NCH   = 9;                  // channels
constexpr int NRB   = 8;                  // radial basis / transformed
constexpr int NEL   = NRB * NLA * NCH;    // 1440 elements per node tensor
constexpr float CUT = 5.5f;
constexpr float MPN = 0.316227766016837933f;  // 1/sqrt(10)

__constant__ int   c_LOF[NLA]  = {0,1,1,1,2,2,2,2,2,2,3,3,3,3,3,3,3,3,3,3};
__constant__ float c_PREF[NLA] = {1,1,1,1,1,2,2,1,2,1,1,3,3,3,6,3,1,3,3,1};
__constant__ int   c_GB[5] = {0,0,1,4,10};   // symmetrize group begin (l5=1..4)
__constant__ int   c_GE[5] = {0,1,4,10,20};  // symmetrize group end

__global__ void k_emb(const int* __restrict__ an, const float* __restrict__ W_emb,
                      float* __restrict__ nemb) {
  int n = blockIdx.x * blockDim.x + threadIdx.x;
  if (n >= NNODE) return;
  int a = an[n];
  int sp = (a == 1) ? 0 : (a == 6) ? 1 : (a == 7) ? 2 : 3;
  nemb[n*3+0] = W_emb[sp*3+0];
  nemb[n*3+1] = W_emb[sp*3+1];
  nemb[n*3+2] = W_emb[sp*3+2];
}

// Per-edge factors: fac[j][e], j: 0..7 = rc (bessel*cutoff), 8..27 = angular, 28..36 = enc
__global__ void k_edge(const float* __restrict__ pos, const float* __restrict__ shifts,
                       const int* __restrict__ ei, const float* __restrict__ nemb,
                       float* __restrict__ fac, int* __restrict__ counts) {
  int e = blockIdx.x * blockDim.x + threadIdx.x;
  if (e >= NEDGE) return;
  int snd = ei[e];
  int rcv = ei[NEDGE + e];
  float vx = pos[rcv*3+0] - pos[snd*3+0] + shifts[e*3+0];
  float vy = pos[rcv*3+1] - pos[snd*3+1] + shifts[e*3+1];
  float vz = pos[rcv*3+2] - pos[snd*3+2] + shifts[e*3+2];
  float len = sqrtf(vx*vx + vy*vy + vz*vz);
  float inv = 1.0f / len;
  float x = vx*inv, y = vy*inv, z = vz*inv;
  float u  = len * (1.0f/CUT);
  float u2 = u*u;
  float u6 = u2*u2*u2;
  float fcut = 1.0f - 28.0f*u6 + 48.0f*u6*u - 21.0f*u6*u2;
  if (u >= 1.0f) fcut = 0.0f;
  float pre = sqrtf(2.0f/CUT) * fcut * inv;
  #pragma unroll
  for (int j = 0; j < NRB; ++j)
    fac[j*NEDGE + e] = pre * sinf((float)(j+1) * M_PIf * u);
  float ang[NLA];
  ang[0]=1.0f; ang[1]=x; ang[2]=y; ang[3]=z;
  ang[4]=x*x; ang[5]=x*y; ang[6]=x*z; ang[7]=y*y; ang[8]=y*z; ang[9]=z*z;
  ang[10]=ang[4]*x; ang[11]=ang[4]*y; ang[12]=ang[4]*z;
  ang[13]=x*ang[7]; ang[14]=ang[5]*z; ang[15]=x*ang[9];
  ang[16]=ang[7]*y; ang[17]=ang[7]*z; ang[18]=y*ang[9]; ang[19]=ang[9]*z;
  #pragma unroll
  for (int i = 0; i < NLA; ++i) fac[(NRB+i)*NEDGE + e] = ang[i];
  float es0=nemb[snd*3+0], es1=nemb[snd*3+1], es2=nemb[snd*3+2];
  float er0=nemb[rcv*3+0], er1=nemb[rcv*3+1], er2=nemb[rcv*3+2];
  fac[(28+0)*NEDGE+e]=es0*er0; fac[(28+1)*NEDGE+e]=es0*er1; fac[(28+2)*NEDGE+e]=es0*er2;
  fac[(28+3)*NEDGE+e]=es1*er0; fac[(28+4)*NEDGE+e]=es1*er1; fac[(28+5)*NEDGE+e]=es1*er2;
  fac[(28+6)*NEDGE+e]=es2*er0; fac[(28+7)*NEDGE+e]=es2*er1; fac[(28+8)*NEDGE+e]=es2*er2;
  atomicAdd(&counts[rcv], 1);
}

__global__ void k_scan(const int* __restrict__ counts, int* __restrict__ offsets,
                       int* __restrict__ cursor) {
  __shared__ int lds[1024];
  int t = threadIdx.x;
  int base = t*4;
  int c0 = (base+0 < NNODE) ? counts[base+0] : 0;
  int c1 = (base+1 < NNODE) ? counts[base+1] : 0;
  int c2 = (base+2 < NNODE) ? counts[base+2] : 0;
  int c3 = (base+3 < NNODE) ? counts[base+3] : 0;
  lds[t] = c0+c1+c2+c3;
  __syncthreads();
  for (int d = 1; d < 1024; d <<= 1) {
    int v = (t >= d) ? lds[t-d] : 0;
    __syncthreads();
    lds[t] += v;
    __syncthreads();
  }
  int excl = (t == 0) ? 0 : lds[t-1];
  int o0 = excl, o1 = o0+c0, o2 = o1+c1, o3 = o2+c2;
  if (base+0 < NNODE) { offsets[base+0]=o0; cursor[base+0]=o0; }
  if (base+1 < NNODE) { offsets[base+1]=o1; cursor[base+1]=o1; }
  if (base+2 < NNODE) { offsets[base+2]=o2; cursor[base+2]=o2; }
  if (base+3 < NNODE) { offsets[base+3]=o3; cursor[base+3]=o3; }
  if (t == 1023) offsets[NNODE] = lds[1023];
}

__global__ void k_scatter(const int* __restrict__ ei, int* __restrict__ cursor,
                          int* __restrict__ order) {
  int e = blockIdx.x * blockDim.x + threadIdx.x;
  if (e >= NEDGE) return;
  int rcv = ei[NEDGE + e];
  int p = atomicAdd(&cursor[rcv], 1);
  order[p] = e;
}

// Per node: accumulate rank-1 edge contributions, radial transform, symmetrize, chi.
__global__ __launch_bounds__(256) void k_nodeA(
    const float* __restrict__ fac, const int* __restrict__ offsets,
    const int* __restrict__ order, const float* __restrict__ W_rt,
    float* __restrict__ A1, float* __restrict__ chi, float* __restrict__ out) {
  __shared__ float s_wrt[256];
  __shared__ float s_tile[NEL];
  __shared__ float s_fac[37];
  __shared__ float s_B[360];
  int n = blockIdx.x, t = threadIdx.x;
  s_wrt[t] = W_rt[t];
  int rr[6], ii[6], cc[6], ll[6];
  bool av[6];
  #pragma unroll
  for (int k = 0; k < 6; ++k) {
    int m = t + k*256;
    av[k] = (m < NEL);
    int mc = av[k] ? m : 0;
    rr[k] = mc / 180;
    int rem = mc % 180;
    ii[k] = rem / 9;
    cc[k] = rem % 9;
    ll[k] = c_LOF[ii[k]];
  }
  float acc[6] = {0,0,0,0,0,0};
  int beg = offsets[n], end = offsets[n+1];
  for (int p = beg; p < end; ++p) {
    int e = order[p];
    __syncthreads();
    if (t < 37) s_fac[t] = fac[t*NEDGE + e];
    __syncthreads();
    #pragma unroll
    for (int k = 0; k < 6; ++k)
      if (av[k]) acc[k] += s_fac[rr[k]] * s_fac[8+ii[k]] * s_fac[28+cc[k]];
  }
  __syncthreads();
  #pragma unroll
  for (int k = 0; k < 6; ++k) if (av[k]) s_tile[t + k*256] = acc[k];
  __syncthreads();
  float a1v[6];
  #pragma unroll
  for (int k = 0; k < 6; ++k) {
    if (av[k]) {
      int ic = ii[k]*9 + cc[k];
      float v = 0.f;
      #pragma unroll
      for (int r = 0; r < NRB; ++r)
        v += s_tile[r*180 + ic] * s_wrt[ll[k]*64 + r*8 + rr[k]];
      a1v[k] = v;
      A1[(size_t)n*NEL + t + k*256] = v;
    }
  }
  __syncthreads();
  #pragma unroll
  for (int k = 0; k < 6; ++k) if (av[k]) s_tile[t + k*256] = a1v[k];
  __syncthreads();
  #pragma unroll
  for (int k2 = 0; k2 < 2; ++k2) {
    int m2 = t + k2*256;
    if (m2 < 360) {
      int s  = m2 / 45;
      int rm = m2 % 45;
      int l5 = rm / 9;
      int c  = rm % 9;
      float b;
      if (l5 == 0) b = s_tile[s*180 + c];
      else {
        b = 0.f;
        for (int i = c_GB[l5]; i < c_GE[l5]; ++i) {
          float v = s_tile[s*180 + i*9 + c];
          b += c_PREF[i]*v*v;
        }
      }
      out[(size_t)(((n*8 + s)*5 + l5)*9 + c)*2 + 0] = b;
      s_B[m2] = b;
    }
  }
  __syncthreads();
  if (t < 9) {
    float x = 0.f;
    #pragma unroll
    for (int j = 0; j < 40; ++j) x += s_B[j*9 + t];
    chi[n*9 + t] = x;
  }
}

// Message-passing round: accB (rank-1 * chi[sender]) + accA (A1[sender]*rc gather),
// then transform, combine with memory term, symmetrize -> feats[1].
__global__ __launch_bounds__(256) void k_nodeMP(
    const float* __restrict__ fac, const int* __restrict__ offsets,
    const int* __restrict__ order, const int* __restrict__ ei,
    const float* __restrict__ W_rt, const float* __restrict__ W_nm,
    const float* __restrict__ A1, const float* __restrict__ chi,
    float* __restrict__ out) {
  __shared__ float s_wrt[256];
  __shared__ float s_wnm[288];
  __shared__ float s_tile[NEL];
  __shared__ float s_fac[37];
  __shared__ float s_chi[9];
  int n = blockIdx.x, t = threadIdx.x;
  s_wrt[t] = W_rt[t];
  s_wnm[t] = W_nm[t];
  if (t < 32) s_wnm[256 + t] = W_nm[256 + t];
  int rr[6], ii[6], cc[6], ll[6];
  bool av[6];
  #pragma unroll
  for (int k = 0; k < 6; ++k) {
    int m = t + k*256;
    av[k] = (m < NEL);
    int mc = av[k] ? m : 0;
    rr[k] = mc / 180;
    int rem = mc % 180;
    ii[k] = rem / 9;
    cc[k] = rem % 9;
    ll[k] = c_LOF[ii[k]];
  }
  float accA[6] = {0,0,0,0,0,0};
  float accB[6] = {0,0,0,0,0,0};
  int beg = offsets[n], end = offsets[n+1];
  for (int p = beg; p < end; ++p) {
    int e = order[p];
    int snd = ei[e];
    __syncthreads();
    if (t < 37) s_fac[t] = fac[t*NEDGE + e];
    else if (t < 46) s_chi[t-37] = chi[snd*9 + (t-37)];
    __syncthreads();
    const float* As = A1 + (size_t)snd*NEL;
    #pragma unroll
    for (int k = 0; k < 6; ++k) {
      if (av[k]) {
        float rv = s_fac[rr[k]];
        accA[k] += As[t + k*256] * rv;
        accB[k] += rv * s_fac[8+ii[k]] * (s_fac[28+cc[k]] * s_chi[cc[k]]);
      }
    }
  }
  __syncthreads();
  #pragma unroll
  for (int k = 0; k < 6; ++k) if (av[k]) s_tile[t + k*256] = accB[k];
  __syncthreads();
  float a2v[6];
  #pragma unroll
  for (int k = 0; k < 6; ++k) {
    if (av[k]) {
      int ic = ii[k]*9 + cc[k];
      float ab = 0.f;
      #pragma unroll
      for (int r = 0; r < NRB; ++r)
        ab += s_tile[r*180 + ic] * s_wrt[ll[k]*64 + r*8 + rr[k]];
      float mem = A1[(size_t)n*NEL + t + k*256] * s_wnm[rr[k]*36 + ll[k]*9 + cc[k]];
      a2v[k] = (ab + accA[k])*MPN + mem;
    }
  }
  __syncthreads();
  #pragma unroll
  for (int k = 0; k < 6; ++k) if (av[k]) s_tile[t + k*256] = a2v[k];
  __syncthreads();
  #pragma unroll
  for (int k2 = 0; k2 < 2; ++k2) {
    int m2 = t + k2*256;
    if (m2 < 360) {
      int s  = m2 / 45;
      int rm = m2 % 45;
      int l5 = rm / 9;
      int c  = rm % 9;
      float b;
      if (l5 == 0) b = s_tile[s*180 + c];
      else {
        b = 0.f;
        for (int i = c_GB[l5]; i < c_GE[l5]; ++i) {
          float v = s_tile[s*180 + i*9 + c];
          b += c_PREF[i]*v*v;
        }
      }
      out[(size_t)(((n*8 + s)*5 + l5)*9 + c)*2 + 1] = b;
    }
  }
}

extern "C" void kernel_launch(void* const* d_in, const int* in_sizes, int n_in,
                              void* d_out, int out_size, void* d_ws, size_t ws_size,
                              hipStream_t stream) {
  const float* pos    = (const float*)d_in[0];
  const float* shifts = (const float*)d_in[1];
  const float* W_emb  = (const float*)d_in[2];
  const float* W_rt   = (const float*)d_in[3];
  const float* W_nm   = (const float*)d_in[4];
  const int*   an     = (const int*)d_in[5];
  const int*   ei     = (const int*)d_in[6];
  float* out = (float*)d_out;

  char* ws = (char*)d_ws;
  size_t off = 0;
  auto carve = [&](size_t bytes) {
    void* p = ws + off;
    off = (off + bytes + 255) & ~(size_t)255;
    return p;
  };
  float* nemb    = (float*)carve((size_t)NNODE*3*sizeof(float));
  float* fac     = (float*)carve((size_t)37*NEDGE*sizeof(float));
  float* A1      = (float*)carve((size_t)NNODE*NEL*sizeof(float));
  float* chi     = (float*)carve((size_t)NNODE*NCH*sizeof(float));
  int*   counts  = (int*)carve((size_t)NNODE*sizeof(int));
  int*   offsets = (int*)carve((size_t)(NNODE+1)*sizeof(int));
  int*   cursor  = (int*)carve((size_t)NNODE*sizeof(int));
  int*   order   = (int*)carve((size_t)NEDGE*sizeof(int));

  hipMemsetAsync(counts, 0, (size_t)NNODE*sizeof(int), stream);
  k_emb<<<(NNODE+255)/256, 256, 0, stream>>>(an, W_emb, nemb);
  k_edge<<<(NEDGE+255)/256, 256, 0, stream>>>(pos, shifts, ei, nemb, fac, counts);
  k_scan<<<1, 1024, 0, stream>>>(counts, offsets, cursor);
  k_scatter<<<(NEDGE+255)/256, 256, 0, stream>>>(ei, cursor, order);
  k_nodeA<<<NNODE, 256, 0, stream>>>(fac, offsets, order, W_rt, A1, chi, out);
  k_nodeMP<<<NNODE, 256, 0, stream>>>(fac, offsets, order, ei, W_rt, W_nm, A1, chi, out);
}

// Round 3
// 156.326 us; speedup vs baseline: 1.3802x; 1.3802x over previous
//
#include <hip/hip_runtime.h>

#ifndef M_PIf
#define M_PIf 3.14159265358979323846f
#endif

constexpr int NNODE = 4000;
constexpr int NEDGE = 48000;
constexpr int NLA   = 20;                 // angular terms
constexpr int NCH   = 9;                  // channels
constexpr int NRB   = 8;                  // radial basis / transformed
constexpr int NEL   = NRB * NLA * NCH;    // 1440 elements per node tensor
constexpr int FW    = 40;                 // padded per-edge factor width
constexpr int EC    = 64;                 // edge chunk per LDS stage
constexpr float CUT = 5.5f;
constexpr float MPN = 0.316227766016837933f;  // 1/sqrt(10)

__constant__ int   c_LOF[NLA]  = {0,1,1,1,2,2,2,2,2,2,3,3,3,3,3,3,3,3,3,3};
__constant__ float c_PREF[NLA] = {1,1,1,1,1,2,2,1,2,1,1,3,3,3,6,3,1,3,3,1};
__constant__ int   c_GB[5] = {0,0,1,4,10};
__constant__ int   c_GE[5] = {0,1,4,10,20};

__global__ void k_emb(const int* __restrict__ an, const float* __restrict__ W_emb,
                      float* __restrict__ nemb) {
  int n = blockIdx.x * blockDim.x + threadIdx.x;
  if (n >= NNODE) return;
  int a = an[n];
  int sp = (a == 1) ? 0 : (a == 6) ? 1 : (a == 7) ? 2 : 3;
  nemb[n*3+0] = W_emb[sp*3+0];
  nemb[n*3+1] = W_emb[sp*3+1];
  nemb[n*3+2] = W_emb[sp*3+2];
}

__global__ void k_count(const int* __restrict__ ei, int* __restrict__ counts) {
  int e = blockIdx.x * blockDim.x + threadIdx.x;
  if (e >= NEDGE) return;
  atomicAdd(&counts[ei[NEDGE + e]], 1);
}

__global__ void k_scan(const int* __restrict__ counts, int* __restrict__ offsets,
                       int* __restrict__ cursor) {
  __shared__ int lds[1024];
  int t = threadIdx.x;
  int base = t*4;
  int c0 = (base+0 < NNODE) ? counts[base+0] : 0;
  int c1 = (base+1 < NNODE) ? counts[base+1] : 0;
  int c2 = (base+2 < NNODE) ? counts[base+2] : 0;
  int c3 = (base+3 < NNODE) ? counts[base+3] : 0;
  lds[t] = c0+c1+c2+c3;
  __syncthreads();
  for (int d = 1; d < 1024; d <<= 1) {
    int v = (t >= d) ? lds[t-d] : 0;
    __syncthreads();
    lds[t] += v;
    __syncthreads();
  }
  int excl = (t == 0) ? 0 : lds[t-1];
  int o0 = excl, o1 = o0+c0, o2 = o1+c1, o3 = o2+c2;
  if (base+0 < NNODE) { offsets[base+0]=o0; cursor[base+0]=o0; }
  if (base+1 < NNODE) { offsets[base+1]=o1; cursor[base+1]=o1; }
  if (base+2 < NNODE) { offsets[base+2]=o2; cursor[base+2]=o2; }
  if (base+3 < NNODE) { offsets[base+3]=o3; cursor[base+3]=o3; }
  if (t == 1023) offsets[NNODE] = lds[1023];
}

// Factors in CSR order, edge-major: facS[p][0..7]=rc, [8..27]=ang, [28..36]=enc
__global__ void k_edgec(const float* __restrict__ pos, const float* __restrict__ shifts,
                        const int* __restrict__ ei, const float* __restrict__ nemb,
                        int* __restrict__ cursor, float* __restrict__ facS,
                        int* __restrict__ sndS) {
  int e = blockIdx.x * blockDim.x + threadIdx.x;
  if (e >= NEDGE) return;
  int snd = ei[e];
  int rcv = ei[NEDGE + e];
  float vx = pos[rcv*3+0] - pos[snd*3+0] + shifts[e*3+0];
  float vy = pos[rcv*3+1] - pos[snd*3+1] + shifts[e*3+1];
  float vz = pos[rcv*3+2] - pos[snd*3+2] + shifts[e*3+2];
  float len = sqrtf(vx*vx + vy*vy + vz*vz);
  float inv = 1.0f / len;
  float x = vx*inv, y = vy*inv, z = vz*inv;
  float u  = len * (1.0f/CUT);
  float u2 = u*u;
  float u6 = u2*u2*u2;
  float fcut = 1.0f - 28.0f*u6 + 48.0f*u6*u - 21.0f*u6*u2;
  if (u >= 1.0f) fcut = 0.0f;
  float pre = sqrtf(2.0f/CUT) * fcut * inv;
  int p = atomicAdd(&cursor[rcv], 1);
  float* f = facS + (size_t)p*FW;
  #pragma unroll
  for (int j = 0; j < NRB; ++j)
    f[j] = pre * sinf((float)(j+1) * M_PIf * u);
  float ang[NLA];
  ang[0]=1.0f; ang[1]=x; ang[2]=y; ang[3]=z;
  ang[4]=x*x; ang[5]=x*y; ang[6]=x*z; ang[7]=y*y; ang[8]=y*z; ang[9]=z*z;
  ang[10]=ang[4]*x; ang[11]=ang[4]*y; ang[12]=ang[4]*z;
  ang[13]=x*ang[7]; ang[14]=ang[5]*z; ang[15]=x*ang[9];
  ang[16]=ang[7]*y; ang[17]=ang[7]*z; ang[18]=y*ang[9]; ang[19]=ang[9]*z;
  #pragma unroll
  for (int i = 0; i < NLA; ++i) f[8+i] = ang[i];
  float es0=nemb[snd*3+0], es1=nemb[snd*3+1], es2=nemb[snd*3+2];
  float er0=nemb[rcv*3+0], er1=nemb[rcv*3+1], er2=nemb[rcv*3+2];
  f[28]=es0*er0; f[29]=es0*er1; f[30]=es0*er2;
  f[31]=es1*er0; f[32]=es1*er1; f[33]=es1*er2;
  f[34]=es2*er0; f[35]=es2*er1; f[36]=es2*er2;
  f[37]=0.f; f[38]=0.f; f[39]=0.f;
  sndS[p] = snd;
}

// Per node: rank-1 accumulate (all edge factors staged in LDS once), radial
// transform, symmetrize, chi. No barriers inside the edge loop.
__global__ __launch_bounds__(256) void k_nodeA(
    const float* __restrict__ facS, const int* __restrict__ offsets,
    const float* __restrict__ W_rt,
    float* __restrict__ A1, float* __restrict__ chi, float* __restrict__ out) {
  __shared__ float s_wrt[256];
  __shared__ float s_e[EC*FW];
  __shared__ float s_tile[NEL];
  __shared__ float s_B[360];
  int n = blockIdx.x, t = threadIdx.x;
  s_wrt[t] = W_rt[t];
  int rr[6], ii[6], cc[6], ll[6];
  bool av[6];
  #pragma unroll
  for (int k = 0; k < 6; ++k) {
    int m = t + k*256;
    av[k] = (m < NEL);
    int mc = av[k] ? m : 0;
    rr[k] = mc / 180;
    int rem = mc % 180;
    ii[k] = rem / 9;
    cc[k] = rem % 9;
    ll[k] = c_LOF[ii[k]];
  }
  float acc[6] = {0,0,0,0,0,0};
  int beg = offsets[n], end = offsets[n+1];
  const float4* f4 = (const float4*)facS;
  for (int base = beg; base < end; base += EC) {
    int m = min(EC, end - base);
    __syncthreads();
    for (int idx = t; idx < m*(FW/4); idx += 256)
      ((float4*)s_e)[idx] = f4[(size_t)base*(FW/4) + idx];
    __syncthreads();
    int p = 0;
    for (; p + 1 < m; p += 2) {
      const float* e0 = s_e + p*FW;
      const float* e1 = e0 + FW;
      #pragma unroll
      for (int k = 0; k < 6; ++k)
        if (av[k])
          acc[k] += e0[rr[k]]*e0[8+ii[k]]*e0[28+cc[k]]
                  + e1[rr[k]]*e1[8+ii[k]]*e1[28+cc[k]];
    }
    if (p < m) {
      const float* e0 = s_e + p*FW;
      #pragma unroll
      for (int k = 0; k < 6; ++k)
        if (av[k]) acc[k] += e0[rr[k]]*e0[8+ii[k]]*e0[28+cc[k]];
    }
  }
  __syncthreads();
  #pragma unroll
  for (int k = 0; k < 6; ++k) if (av[k]) s_tile[t + k*256] = acc[k];
  __syncthreads();
  float a1v[6];
  #pragma unroll
  for (int k = 0; k < 6; ++k) {
    if (av[k]) {
      int ic = ii[k]*9 + cc[k];
      float v = 0.f;
      #pragma unroll
      for (int r = 0; r < NRB; ++r)
        v += s_tile[r*180 + ic] * s_wrt[ll[k]*64 + r*8 + rr[k]];
      a1v[k] = v;
      A1[(size_t)n*NEL + t + k*256] = v;
    }
  }
  __syncthreads();
  #pragma unroll
  for (int k = 0; k < 6; ++k) if (av[k]) s_tile[t + k*256] = a1v[k];
  __syncthreads();
  #pragma unroll
  for (int k2 = 0; k2 < 2; ++k2) {
    int m2 = t + k2*256;
    if (m2 < 360) {
      int s  = m2 / 45;
      int rm = m2 % 45;
      int l5 = rm / 9;
      int c  = rm % 9;
      float b;
      if (l5 == 0) b = s_tile[s*180 + c];
      else {
        b = 0.f;
        for (int i = c_GB[l5]; i < c_GE[l5]; ++i) {
          float v = s_tile[s*180 + i*9 + c];
          b += c_PREF[i]*v*v;
        }
      }
      out[(size_t)(((n*8 + s)*5 + l5)*9 + c)*2 + 0] = b;
      s_B[m2] = b;
    }
  }
  __syncthreads();
  if (t < 9) {
    float x = 0.f;
    #pragma unroll
    for (int j = 0; j < 40; ++j) x += s_B[j*9 + t];
    chi[n*9 + t] = x;
  }
}

// MP round: accB (rank-1 with enc*chi[sender] prestaged) + accA (A1[sender]*rc
// gathers, pipelined, no barriers in loop), transform, memory term, symmetrize.
__global__ __launch_bounds__(256) void k_nodeMP(
    const float* __restrict__ facS, const int* __restrict__ offsets,
    const int* __restrict__ sndS,
    const float* __restrict__ W_rt, const float* __restrict__ W_nm,
    const float* __restrict__ A1, const float* __restrict__ chi,
    float* __restrict__ out) {
  __shared__ float s_wrt[256];
  __shared__ float s_wnm[288];
  __shared__ float s_e[EC*FW];
  __shared__ float s_echi[EC*12];
  __shared__ int   s_snd[EC];
  __shared__ float s_tile[NEL];
  int n = blockIdx.x, t = threadIdx.x;
  s_wrt[t] = W_rt[t];
  s_wnm[t] = W_nm[t];
  if (t < 32) s_wnm[256 + t] = W_nm[256 + t];
  int rr[6], ii[6], cc[6], ll[6];
  bool av[6];
  #pragma unroll
  for (int k = 0; k < 6; ++k) {
    int m = t + k*256;
    av[k] = (m < NEL);
    int mc = av[k] ? m : 0;
    rr[k] = mc / 180;
    int rem = mc % 180;
    ii[k] = rem / 9;
    cc[k] = rem % 9;
    ll[k] = c_LOF[ii[k]];
  }
  float accA[6] = {0,0,0,0,0,0};
  float accB[6] = {0,0,0,0,0,0};
  // memory term read early (independent of edge loop)
  float mymem[6];
  #pragma unroll
  for (int k = 0; k < 6; ++k)
    mymem[k] = av[k] ? A1[(size_t)n*NEL + t + k*256] : 0.f;
  int beg = offsets[n], end = offsets[n+1];
  const float4* f4 = (const float4*)facS;
  for (int base = beg; base < end; base += EC) {
    int m = min(EC, end - base);
    __syncthreads();
    for (int idx = t; idx < m*(FW/4); idx += 256)
      ((float4*)s_e)[idx] = f4[(size_t)base*(FW/4) + idx];
    for (int idx = t; idx < m; idx += 256) s_snd[idx] = sndS[base + idx];
    __syncthreads();
    for (int idx = t; idx < m*9; idx += 256) {
      int p = idx / 9, c = idx - p*9;
      s_echi[p*12 + c] = chi[sndS[base + p]*9 + c] * s_e[p*FW + 28 + c];
    }
    __syncthreads();
    int p = 0;
    for (; p + 1 < m; p += 2) {
      const float* e0 = s_e + p*FW;
      const float* e1 = e0 + FW;
      const float* A0p = A1 + (size_t)s_snd[p]*NEL + t;
      const float* A1p = A1 + (size_t)s_snd[p+1]*NEL + t;
      const float* x0 = s_echi + p*12;
      const float* x1 = x0 + 12;
      #pragma unroll
      for (int k = 0; k < 6; ++k) {
        if (av[k]) {
          float r0 = e0[rr[k]], r1 = e1[rr[k]];
          accA[k] += A0p[k*256]*r0 + A1p[k*256]*r1;
          accB[k] += r0*e0[8+ii[k]]*x0[cc[k]] + r1*e1[8+ii[k]]*x1[cc[k]];
        }
      }
    }
    if (p < m) {
      const float* e0 = s_e + p*FW;
      const float* A0p = A1 + (size_t)s_snd[p]*NEL + t;
      const float* x0 = s_echi + p*12;
      #pragma unroll
      for (int k = 0; k < 6; ++k) {
        if (av[k]) {
          float r0 = e0[rr[k]];
          accA[k] += A0p[k*256]*r0;
          accB[k] += r0*e0[8+ii[k]]*x0[cc[k]];
        }
      }
    }
  }
  __syncthreads();
  #pragma unroll
  for (int k = 0; k < 6; ++k) if (av[k]) s_tile[t + k*256] = accB[k];
  __syncthreads();
  float a2v[6];
  #pragma unroll
  for (int k = 0; k < 6; ++k) {
    if (av[k]) {
      int ic = ii[k]*9 + cc[k];
      float ab = 0.f;
      #pragma unroll
      for (int r = 0; r < NRB; ++r)
        ab += s_tile[r*180 + ic] * s_wrt[ll[k]*64 + r*8 + rr[k]];
      float mem = mymem[k] * s_wnm[rr[k]*36 + ll[k]*9 + cc[k]];
      a2v[k] = (ab + accA[k])*MPN + mem;
    }
  }
  __syncthreads();
  #pragma unroll
  for (int k = 0; k < 6; ++k) if (av[k]) s_tile[t + k*256] = a2v[k];
  __syncthreads();
  #pragma unroll
  for (int k2 = 0; k2 < 2; ++k2) {
    int m2 = t + k2*256;
    if (m2 < 360) {
      int s  = m2 / 45;
      int rm = m2 % 45;
      int l5 = rm / 9;
      int c  = rm % 9;
      float b;
      if (l5 == 0) b = s_tile[s*180 + c];
      else {
        b = 0.f;
        for (int i = c_GB[l5]; i < c_GE[l5]; ++i) {
          float v = s_tile[s*180 + i*9 + c];
          b += c_PREF[i]*v*v;
        }
      }
      out[(size_t)(((n*8 + s)*5 + l5)*9 + c)*2 + 1] = b;
    }
  }
}

extern "C" void kernel_launch(void* const* d_in, const int* in_sizes, int n_in,
                              void* d_out, int out_size, void* d_ws, size_t ws_size,
                              hipStream_t stream) {
  const float* pos    = (const float*)d_in[0];
  const float* shifts = (const float*)d_in[1];
  const float* W_emb  = (const float*)d_in[2];
  const float* W_rt   = (const float*)d_in[3];
  const float* W_nm   = (const float*)d_in[4];
  const int*   an     = (const int*)d_in[5];
  const int*   ei     = (const int*)d_in[6];
  float* out = (float*)d_out;

  char* ws = (char*)d_ws;
  size_t off = 0;
  auto carve = [&](size_t bytes) {
    void* p = ws + off;
    off = (off + bytes + 255) & ~(size_t)255;
    return p;
  };
  float* nemb    = (float*)carve((size_t)NNODE*3*sizeof(float));
  float* facS    = (float*)carve((size_t)FW*NEDGE*sizeof(float));
  int*   sndS    = (int*)carve((size_t)NEDGE*sizeof(int));
  float* A1      = (float*)carve((size_t)NNODE*NEL*sizeof(float));
  float* chi     = (float*)carve((size_t)NNODE*NCH*sizeof(float));
  int*   counts  = (int*)carve((size_t)NNODE*sizeof(int));
  int*   offsets = (int*)carve((size_t)(NNODE+1)*sizeof(int));
  int*   cursor  = (int*)carve((size_t)NNODE*sizeof(int));

  hipMemsetAsync(counts, 0, (size_t)NNODE*sizeof(int), stream);
  k_emb<<<(NNODE+255)/256, 256, 0, stream>>>(an, W_emb, nemb);
  k_count<<<(NEDGE+255)/256, 256, 0, stream>>>(ei, counts);
  k_scan<<<1, 1024, 0, stream>>>(counts, offsets, cursor);
  k_edgec<<<(NEDGE+255)/256, 256, 0, stream>>>(pos, shifts, ei, nemb, cursor, facS, sndS);
  k_nodeA<<<NNODE, 256, 0, stream>>>(facS, offsets, W_rt, A1, chi, out);
  k_nodeMP<<<NNODE, 256, 0, stream>>>(facS, offsets, sndS, W_rt, W_nm, A1, chi, out);
}

// Round 4
// 133.355 us; speedup vs baseline: 1.6179x; 1.1723x over previous
//
#include <hip/hip_runtime.h>
#include <hip/hip_fp16.h>

#ifndef M_PIf
#define M_PIf 3.14159265358979323846f
#endif

constexpr int NNODE = 4000;
constexpr int NEDGE = 48000;
constexpr int NLA   = 20;                 // angular terms
constexpr int NCH   = 9;                  // channels
constexpr int NRB   = 8;                  // radial basis / transformed
constexpr int NEL   = NRB * NLA * NCH;    // 1440 elements per node tensor
constexpr int NP2   = NEL / 2;            // 720 half2 pairs
constexpr int FW    = 40;                 // padded per-edge factor width
constexpr int EC    = 64;                 // edge chunk per LDS stage
constexpr float CUT = 5.5f;
constexpr float MPN = 0.316227766016837933f;  // 1/sqrt(10)

__constant__ int   c_LOF[NLA]  = {0,1,1,1,2,2,2,2,2,2,3,3,3,3,3,3,3,3,3,3};
__constant__ float c_PREF[NLA] = {1,1,1,1,1,2,2,1,2,1,1,3,3,3,6,3,1,3,3,1};
__constant__ int   c_GB[5] = {0,0,1,4,10};
__constant__ int   c_GE[5] = {0,1,4,10,20};

__global__ void k_emb(const int* __restrict__ an, const float* __restrict__ W_emb,
                      float* __restrict__ nemb) {
  int n = blockIdx.x * blockDim.x + threadIdx.x;
  if (n >= NNODE) return;
  int a = an[n];
  int sp = (a == 1) ? 0 : (a == 6) ? 1 : (a == 7) ? 2 : 3;
  nemb[n*3+0] = W_emb[sp*3+0];
  nemb[n*3+1] = W_emb[sp*3+1];
  nemb[n*3+2] = W_emb[sp*3+2];
}

__global__ void k_count(const int* __restrict__ ei, int* __restrict__ counts) {
  int e = blockIdx.x * blockDim.x + threadIdx.x;
  if (e >= NEDGE) return;
  atomicAdd(&counts[ei[NEDGE + e]], 1);
}

__global__ void k_scan(const int* __restrict__ counts, int* __restrict__ offsets,
                       int* __restrict__ cursor) {
  __shared__ int lds[1024];
  int t = threadIdx.x;
  int base = t*4;
  int c0 = (base+0 < NNODE) ? counts[base+0] : 0;
  int c1 = (base+1 < NNODE) ? counts[base+1] : 0;
  int c2 = (base+2 < NNODE) ? counts[base+2] : 0;
  int c3 = (base+3 < NNODE) ? counts[base+3] : 0;
  lds[t] = c0+c1+c2+c3;
  __syncthreads();
  for (int d = 1; d < 1024; d <<= 1) {
    int v = (t >= d) ? lds[t-d] : 0;
    __syncthreads();
    lds[t] += v;
    __syncthreads();
  }
  int excl = (t == 0) ? 0 : lds[t-1];
  int o0 = excl, o1 = o0+c0, o2 = o1+c1, o3 = o2+c2;
  if (base+0 < NNODE) { offsets[base+0]=o0; cursor[base+0]=o0; }
  if (base+1 < NNODE) { offsets[base+1]=o1; cursor[base+1]=o1; }
  if (base+2 < NNODE) { offsets[base+2]=o2; cursor[base+2]=o2; }
  if (base+3 < NNODE) { offsets[base+3]=o3; cursor[base+3]=o3; }
  if (t == 1023) offsets[NNODE] = lds[1023];
}

// Factors in CSR order, edge-major: facS[p][0..7]=rc, [8..27]=ang, [28..36]=enc
__global__ void k_edgec(const float* __restrict__ pos, const float* __restrict__ shifts,
                        const int* __restrict__ ei, const float* __restrict__ nemb,
                        int* __restrict__ cursor, float* __restrict__ facS,
                        int* __restrict__ sndS) {
  int e = blockIdx.x * blockDim.x + threadIdx.x;
  if (e >= NEDGE) return;
  int snd = ei[e];
  int rcv = ei[NEDGE + e];
  float vx = pos[rcv*3+0] - pos[snd*3+0] + shifts[e*3+0];
  float vy = pos[rcv*3+1] - pos[snd*3+1] + shifts[e*3+1];
  float vz = pos[rcv*3+2] - pos[snd*3+2] + shifts[e*3+2];
  float len = sqrtf(vx*vx + vy*vy + vz*vz);
  float inv = 1.0f / len;
  float x = vx*inv, y = vy*inv, z = vz*inv;
  float u  = len * (1.0f/CUT);
  float u2 = u*u;
  float u6 = u2*u2*u2;
  float fcut = 1.0f - 28.0f*u6 + 48.0f*u6*u - 21.0f*u6*u2;
  if (u >= 1.0f) fcut = 0.0f;
  float pre = sqrtf(2.0f/CUT) * fcut * inv;
  int p = atomicAdd(&cursor[rcv], 1);
  float* f = facS + (size_t)p*FW;
  #pragma unroll
  for (int j = 0; j < NRB; ++j)
    f[j] = pre * sinf((float)(j+1) * M_PIf * u);
  float ang[NLA];
  ang[0]=1.0f; ang[1]=x; ang[2]=y; ang[3]=z;
  ang[4]=x*x; ang[5]=x*y; ang[6]=x*z; ang[7]=y*y; ang[8]=y*z; ang[9]=z*z;
  ang[10]=ang[4]*x; ang[11]=ang[4]*y; ang[12]=ang[4]*z;
  ang[13]=x*ang[7]; ang[14]=ang[5]*z; ang[15]=x*ang[9];
  ang[16]=ang[7]*y; ang[17]=ang[7]*z; ang[18]=y*ang[9]; ang[19]=ang[9]*z;
  #pragma unroll
  for (int i = 0; i < NLA; ++i) f[8+i] = ang[i];
  float es0=nemb[snd*3+0], es1=nemb[snd*3+1], es2=nemb[snd*3+2];
  float er0=nemb[rcv*3+0], er1=nemb[rcv*3+1], er2=nemb[rcv*3+2];
  f[28]=es0*er0; f[29]=es0*er1; f[30]=es0*er2;
  f[31]=es1*er0; f[32]=es1*er1; f[33]=es1*er2;
  f[34]=es2*er0; f[35]=es2*er1; f[36]=es2*er2;
  f[37]=0.f; f[38]=0.f; f[39]=0.f;
  sndS[p] = snd;
}

// Per node: rank-1 accumulate, radial transform, symmetrize, chi.
// Writes fp32 A1 (exact) and f16 A1h (gather copy for the MP round).
__global__ __launch_bounds__(256) void k_nodeA(
    const float* __restrict__ facS, const int* __restrict__ offsets,
    const float* __restrict__ W_rt,
    float* __restrict__ A1, __half* __restrict__ A1h,
    float* __restrict__ chi, float* __restrict__ out) {
  __shared__ float s_wrt[256];
  __shared__ float s_e[EC*FW];
  __shared__ float s_tile[NEL];
  __shared__ float s_B[360];
  int n = blockIdx.x, t = threadIdx.x;
  s_wrt[t] = W_rt[t];
  int rr[6], ii[6], cc[6], ll[6];
  bool av[6];
  #pragma unroll
  for (int k = 0; k < 6; ++k) {
    int m = t + k*256;
    av[k] = (m < NEL);
    int mc = av[k] ? m : 0;
    rr[k] = mc / 180;
    int rem = mc % 180;
    ii[k] = rem / 9;
    cc[k] = rem % 9;
    ll[k] = c_LOF[ii[k]];
  }
  float acc[6] = {0,0,0,0,0,0};
  int beg = offsets[n], end = offsets[n+1];
  const float4* f4 = (const float4*)facS;
  for (int base = beg; base < end; base += EC) {
    int m = min(EC, end - base);
    __syncthreads();
    for (int idx = t; idx < m*(FW/4); idx += 256)
      ((float4*)s_e)[idx] = f4[(size_t)base*(FW/4) + idx];
    __syncthreads();
    int p = 0;
    for (; p + 1 < m; p += 2) {
      const float* e0 = s_e + p*FW;
      const float* e1 = e0 + FW;
      #pragma unroll
      for (int k = 0; k < 6; ++k)
        if (av[k])
          acc[k] += e0[rr[k]]*e0[8+ii[k]]*e0[28+cc[k]]
                  + e1[rr[k]]*e1[8+ii[k]]*e1[28+cc[k]];
    }
    if (p < m) {
      const float* e0 = s_e + p*FW;
      #pragma unroll
      for (int k = 0; k < 6; ++k)
        if (av[k]) acc[k] += e0[rr[k]]*e0[8+ii[k]]*e0[28+cc[k]];
    }
  }
  __syncthreads();
  #pragma unroll
  for (int k = 0; k < 6; ++k) if (av[k]) s_tile[t + k*256] = acc[k];
  __syncthreads();
  float a1v[6];
  #pragma unroll
  for (int k = 0; k < 6; ++k) {
    if (av[k]) {
      int ic = ii[k]*9 + cc[k];
      float v = 0.f;
      #pragma unroll
      for (int r = 0; r < NRB; ++r)
        v += s_tile[r*180 + ic] * s_wrt[ll[k]*64 + r*8 + rr[k]];
      a1v[k] = v;
      A1[(size_t)n*NEL + t + k*256] = v;
      A1h[(size_t)n*NEL + t + k*256] = __float2half(v);
    }
  }
  __syncthreads();
  #pragma unroll
  for (int k = 0; k < 6; ++k) if (av[k]) s_tile[t + k*256] = a1v[k];
  __syncthreads();
  #pragma unroll
  for (int k2 = 0; k2 < 2; ++k2) {
    int m2 = t + k2*256;
    if (m2 < 360) {
      int s  = m2 / 45;
      int rm = m2 % 45;
      int l5 = rm / 9;
      int c  = rm % 9;
      float b;
      if (l5 == 0) b = s_tile[s*180 + c];
      else {
        b = 0.f;
        for (int i = c_GB[l5]; i < c_GE[l5]; ++i) {
          float v = s_tile[s*180 + i*9 + c];
          b += c_PREF[i]*v*v;
        }
      }
      out[(size_t)(((n*8 + s)*5 + l5)*9 + c)*2 + 0] = b;
      s_B[m2] = b;
    }
  }
  __syncthreads();
  if (t < 9) {
    float x = 0.f;
    #pragma unroll
    for (int j = 0; j < 40; ++j) x += s_B[j*9 + t];
    chi[n*9 + t] = x;
  }
}

// MP round: accB (rank-1, LDS) + accA (f16 A1h[sender] half2 gathers, 4-edge
// unrolled, no barriers in loop), transform, memory term, symmetrize.
__global__ __launch_bounds__(256) void k_nodeMP(
    const float* __restrict__ facS, const int* __restrict__ offsets,
    const int* __restrict__ sndS,
    const float* __restrict__ W_rt, const float* __restrict__ W_nm,
    const float* __restrict__ A1, const __half2* __restrict__ A1h2,
    const float* __restrict__ chi, float* __restrict__ out) {
  __shared__ float s_wrt[256];
  __shared__ float s_wnm[288];
  __shared__ float s_e[EC*FW];
  __shared__ float s_echi[EC*12];
  __shared__ int   s_snd[EC];
  __shared__ float s_tile[NEL];
  int n = blockIdx.x, t = threadIdx.x;
  s_wrt[t] = W_rt[t];
  s_wnm[t] = W_nm[t];
  if (t < 32) s_wnm[256 + t] = W_nm[256 + t];
  // half2-pair ownership: pair q_j = t + j*256 (j=0..2), element m = 2q+h
  int qq[3]; bool avp[3];
  int prr[3];           // r-index, same for both halves of a pair (180 even)
  int pii[6], pcc[6], pll[6];
  #pragma unroll
  for (int j = 0; j < 3; ++j) {
    qq[j] = t + j*256;
    avp[j] = (qq[j] < NP2);
    int q = avp[j] ? qq[j] : 0;
    prr[j] = (2*q) / 180;
    #pragma unroll
    for (int h = 0; h < 2; ++h) {
      int m = 2*q + h;
      int rem = m % 180;
      pii[2*j+h] = rem / 9;
      pcc[2*j+h] = rem % 9;
      pll[2*j+h] = c_LOF[rem / 9];
    }
  }
  float accA[6] = {0,0,0,0,0,0};
  float accB[6] = {0,0,0,0,0,0};
  // memory term read early (fp32, independent of edge loop)
  float mymem[6];
  #pragma unroll
  for (int j = 0; j < 3; ++j) {
    if (avp[j]) {
      float2 v = ((const float2*)A1)[(size_t)n*NP2 + qq[j]];
      mymem[2*j+0] = v.x;
      mymem[2*j+1] = v.y;
    } else { mymem[2*j+0] = 0.f; mymem[2*j+1] = 0.f; }
  }
  int beg = offsets[n], end = offsets[n+1];
  const float4* f4 = (const float4*)facS;
  for (int base = beg; base < end; base += EC) {
    int m = min(EC, end - base);
    __syncthreads();
    for (int idx = t; idx < m*(FW/4); idx += 256)
      ((float4*)s_e)[idx] = f4[(size_t)base*(FW/4) + idx];
    for (int idx = t; idx < m; idx += 256) s_snd[idx] = sndS[base + idx];
    __syncthreads();
    for (int idx = t; idx < m*9; idx += 256) {
      int p = idx / 9, c = idx - p*9;
      s_echi[p*12 + c] = chi[s_snd[p]*9 + c] * s_e[p*FW + 28 + c];
    }
    __syncthreads();
    int p = 0;
    for (; p + 3 < m; p += 4) {
      // issue all 12 gathers first
      __half2 g[4][3];
      #pragma unroll
      for (int x = 0; x < 4; ++x) {
        const __half2* Ah = A1h2 + (size_t)s_snd[p+x]*NP2;
        #pragma unroll
        for (int j = 0; j < 3; ++j)
          if (avp[j]) g[x][j] = Ah[qq[j]];
      }
      #pragma unroll
      for (int x = 0; x < 4; ++x) {
        const float* e0 = s_e + (p+x)*FW;
        const float* x0 = s_echi + (p+x)*12;
        #pragma unroll
        for (int j = 0; j < 3; ++j) {
          if (avp[j]) {
            float rv = e0[prr[j]];
            float2 gf = __half22float2(g[x][j]);
            accA[2*j+0] += gf.x * rv;
            accA[2*j+1] += gf.y * rv;
            accB[2*j+0] += rv * e0[8+pii[2*j+0]] * x0[pcc[2*j+0]];
            accB[2*j+1] += rv * e0[8+pii[2*j+1]] * x0[pcc[2*j+1]];
          }
        }
      }
    }
    for (; p < m; ++p) {
      const float* e0 = s_e + p*FW;
      const float* x0 = s_echi + p*12;
      const __half2* Ah = A1h2 + (size_t)s_snd[p]*NP2;
      #pragma unroll
      for (int j = 0; j < 3; ++j) {
        if (avp[j]) {
          float rv = e0[prr[j]];
          float2 gf = __half22float2(Ah[qq[j]]);
          accA[2*j+0] += gf.x * rv;
          accA[2*j+1] += gf.y * rv;
          accB[2*j+0] += rv * e0[8+pii[2*j+0]] * x0[pcc[2*j+0]];
          accB[2*j+1] += rv * e0[8+pii[2*j+1]] * x0[pcc[2*j+1]];
        }
      }
    }
  }
  __syncthreads();
  #pragma unroll
  for (int j = 0; j < 3; ++j)
    if (avp[j]) {
      s_tile[2*qq[j]+0] = accB[2*j+0];
      s_tile[2*qq[j]+1] = accB[2*j+1];
    }
  __syncthreads();
  float a2v[6];
  #pragma unroll
  for (int j = 0; j < 3; ++j) {
    #pragma unroll
    for (int h = 0; h < 2; ++h) {
      int s = 2*j + h;
      if (avp[j]) {
        int ic = pii[s]*9 + pcc[s];
        float ab = 0.f;
        #pragma unroll
        for (int r = 0; r < NRB; ++r)
          ab += s_tile[r*180 + ic] * s_wrt[pll[s]*64 + r*8 + prr[j]];
        float mem = mymem[s] * s_wnm[prr[j]*36 + pll[s]*9 + pcc[s]];
        a2v[s] = (ab + accA[s])*MPN + mem;
      }
    }
  }
  __syncthreads();
  #pragma unroll
  for (int j = 0; j < 3; ++j)
    if (avp[j]) {
      s_tile[2*qq[j]+0] = a2v[2*j+0];
      s_tile[2*qq[j]+1] = a2v[2*j+1];
    }
  __syncthreads();
  #pragma unroll
  for (int k2 = 0; k2 < 2; ++k2) {
    int m2 = t + k2*256;
    if (m2 < 360) {
      int s  = m2 / 45;
      int rm = m2 % 45;
      int l5 = rm / 9;
      int c  = rm % 9;
      float b;
      if (l5 == 0) b = s_tile[s*180 + c];
      else {
        b = 0.f;
        for (int i = c_GB[l5]; i < c_GE[l5]; ++i) {
          float v = s_tile[s*180 + i*9 + c];
          b += c_PREF[i]*v*v;
        }
      }
      out[(size_t)(((n*8 + s)*5 + l5)*9 + c)*2 + 1] = b;
    }
  }
}

extern "C" void kernel_launch(void* const* d_in, const int* in_sizes, int n_in,
                              void* d_out, int out_size, void* d_ws, size_t ws_size,
                              hipStream_t stream) {
  const float* pos    = (const float*)d_in[0];
  const float* shifts = (const float*)d_in[1];
  const float* W_emb  = (const float*)d_in[2];
  const float* W_rt   = (const float*)d_in[3];
  const float* W_nm   = (const float*)d_in[4];
  const int*   an     = (const int*)d_in[5];
  const int*   ei     = (const int*)d_in[6];
  float* out = (float*)d_out;

  char* ws = (char*)d_ws;
  size_t off = 0;
  auto carve = [&](size_t bytes) {
    void* p = ws + off;
    off = (off + bytes + 255) & ~(size_t)255;
    return p;
  };
  float*  nemb    = (float*)carve((size_t)NNODE*3*sizeof(float));
  float*  facS    = (float*)carve((size_t)FW*NEDGE*sizeof(float));
  int*    sndS    = (int*)carve((size_t)NEDGE*sizeof(int));
  float*  A1      = (float*)carve((size_t)NNODE*NEL*sizeof(float));
  __half* A1h     = (__half*)carve((size_t)NNODE*NEL*sizeof(__half));
  float*  chi     = (float*)carve((size_t)NNODE*NCH*sizeof(float));
  int*    counts  = (int*)carve((size_t)NNODE*sizeof(int));
  int*    offsets = (int*)carve((size_t)(NNODE+1)*sizeof(int));
  int*    cursor  = (int*)carve((size_t)NNODE*sizeof(int));

  hipMemsetAsync(counts, 0, (size_t)NNODE*sizeof(int), stream);
  k_emb<<<(NNODE+255)/256, 256, 0, stream>>>(an, W_emb, nemb);
  k_count<<<(NEDGE+255)/256, 256, 0, stream>>>(ei, counts);
  k_scan<<<1, 1024, 0, stream>>>(counts, offsets, cursor);
  k_edgec<<<(NEDGE+255)/256, 256, 0, stream>>>(pos, shifts, ei, nemb, cursor, facS, sndS);
  k_nodeA<<<NNODE, 256, 0, stream>>>(facS, offsets, W_rt, A1, A1h, chi, out);
  k_nodeMP<<<NNODE, 256, 0, stream>>>(facS, offsets, sndS, W_rt, W_nm, A1,
                                      (const __half2*)A1h, chi, out);
}

// Round 7
// 132.842 us; speedup vs baseline: 1.6241x; 1.0039x over previous
//
#include <hip/hip_runtime.h>
#include <hip/hip_fp16.h>

#ifndef M_PIf
#define M_PIf 3.14159265358979323846f
#endif

constexpr int NNODE = 4000;
constexpr int NEDGE = 48000;
constexpr int NLA   = 20;                 // angular terms
constexpr int NCH   = 9;                  // channels
constexpr int NRB   = 8;                  // radial basis / transformed
constexpr int NEL   = NRB * NLA * NCH;    // 1440 elements per node tensor
constexpr int NP2   = NEL / 2;            // 720 half2 pairs
constexpr int FW    = 40;                 // padded per-edge factor width
constexpr int EC    = 32;                 // edge chunk per LDS stage
constexpr float CUT = 5.5f;
constexpr float MPN = 0.316227766016837933f;  // 1/sqrt(10)

__constant__ int   c_LOF[NLA]  = {0,1,1,1,2,2,2,2,2,2,3,3,3,3,3,3,3,3,3,3};
__constant__ float c_PREF[NLA] = {1,1,1,1,1,2,2,1,2,1,1,3,3,3,6,3,1,3,3,1};
__constant__ int   c_GB[4] = {0,0,1,4};   // groups for l5=0..3 (half 0)
__constant__ int   c_GE[4] = {0,1,4,10};

__global__ void k_emb(const int* __restrict__ an, const float* __restrict__ W_emb,
                      float* __restrict__ nemb) {
  int n = blockIdx.x * blockDim.x + threadIdx.x;
  if (n >= NNODE) return;
  int a = an[n];
  int sp = (a == 1) ? 0 : (a == 6) ? 1 : (a == 7) ? 2 : 3;
  nemb[n*3+0] = W_emb[sp*3+0];
  nemb[n*3+1] = W_emb[sp*3+1];
  nemb[n*3+2] = W_emb[sp*3+2];
}

__global__ void k_count(const int* __restrict__ ei, int* __restrict__ counts) {
  int e = blockIdx.x * blockDim.x + threadIdx.x;
  if (e >= NEDGE) return;
  atomicAdd(&counts[ei[NEDGE + e]], 1);
}

__global__ void k_scan(const int* __restrict__ counts, int* __restrict__ offsets,
                       int* __restrict__ cursor) {
  __shared__ int lds[1024];
  int t = threadIdx.x;
  int base = t*4;
  int c0 = (base+0 < NNODE) ? counts[base+0] : 0;
  int c1 = (base+1 < NNODE) ? counts[base+1] : 0;
  int c2 = (base+2 < NNODE) ? counts[base+2] : 0;
  int c3 = (base+3 < NNODE) ? counts[base+3] : 0;
  lds[t] = c0+c1+c2+c3;
  __syncthreads();
  for (int d = 1; d < 1024; d <<= 1) {
    int v = (t >= d) ? lds[t-d] : 0;
    __syncthreads();
    lds[t] += v;
    __syncthreads();
  }
  int excl = (t == 0) ? 0 : lds[t-1];
  int o0 = excl, o1 = o0+c0, o2 = o1+c1, o3 = o2+c2;
  if (base+0 < NNODE) { offsets[base+0]=o0; cursor[base+0]=o0; }
  if (base+1 < NNODE) { offsets[base+1]=o1; cursor[base+1]=o1; }
  if (base+2 < NNODE) { offsets[base+2]=o2; cursor[base+2]=o2; }
  if (base+3 < NNODE) { offsets[base+3]=o3; cursor[base+3]=o3; }
  if (t == 1023) offsets[NNODE] = lds[1023];
}

// Factors in CSR order, edge-major: facS[p][0..7]=rc, [8..27]=ang, [28..36]=enc
__global__ void k_edgec(const float* __restrict__ pos, const float* __restrict__ shifts,
                        const int* __restrict__ ei, const float* __restrict__ nemb,
                        int* __restrict__ cursor, float* __restrict__ facS,
                        int* __restrict__ sndS) {
  int e = blockIdx.x * blockDim.x + threadIdx.x;
  if (e >= NEDGE) return;
  int snd = ei[e];
  int rcv = ei[NEDGE + e];
  float vx = pos[rcv*3+0] - pos[snd*3+0] + shifts[e*3+0];
  float vy = pos[rcv*3+1] - pos[snd*3+1] + shifts[e*3+1];
  float vz = pos[rcv*3+2] - pos[snd*3+2] + shifts[e*3+2];
  float len = sqrtf(vx*vx + vy*vy + vz*vz);
  float inv = 1.0f / len;
  float x = vx*inv, y = vy*inv, z = vz*inv;
  float u  = len * (1.0f/CUT);
  float u2 = u*u;
  float u6 = u2*u2*u2;
  float fcut = 1.0f - 28.0f*u6 + 48.0f*u6*u - 21.0f*u6*u2;
  if (u >= 1.0f) fcut = 0.0f;
  float pre = sqrtf(2.0f/CUT) * fcut * inv;
  int p = atomicAdd(&cursor[rcv], 1);
  float* f = facS + (size_t)p*FW;
  #pragma unroll
  for (int j = 0; j < NRB; ++j)
    f[j] = pre * sinf((float)(j+1) * M_PIf * u);
  float ang[NLA];
  ang[0]=1.0f; ang[1]=x; ang[2]=y; ang[3]=z;
  ang[4]=x*x; ang[5]=x*y; ang[6]=x*z; ang[7]=y*y; ang[8]=y*z; ang[9]=z*z;
  ang[10]=ang[4]*x; ang[11]=ang[4]*y; ang[12]=ang[4]*z;
  ang[13]=x*ang[7]; ang[14]=ang[5]*z; ang[15]=x*ang[9];
  ang[16]=ang[7]*y; ang[17]=ang[7]*z; ang[18]=y*ang[9]; ang[19]=ang[9]*z;
  #pragma unroll
  for (int i = 0; i < NLA; ++i) f[8+i] = ang[i];
  float es0=nemb[snd*3+0], es1=nemb[snd*3+1], es2=nemb[snd*3+2];
  float er0=nemb[rcv*3+0], er1=nemb[rcv*3+1], er2=nemb[rcv*3+2];
  f[28]=es0*er0; f[29]=es0*er1; f[30]=es0*er2;
  f[31]=es1*er0; f[32]=es1*er1; f[33]=es1*er2;
  f[34]=es2*er0; f[35]=es2*er1; f[36]=es2*er2;
  f[37]=0.f; f[38]=0.f; f[39]=0.f;
  sndS[p] = snd;
}

// ---- split-node kernels: block = (node, half); half owns i in [10*half, 10*half+10)
// pair slot j in [0,360): r_out = j/45, kk = j%45; global half2-pair q = r_out*90+kk+45*half

__global__ __launch_bounds__(256, 4) void k_nodeA(
    const float* __restrict__ facS, const int* __restrict__ offsets,
    const float* __restrict__ W_rt,
    float2* __restrict__ A1f2, __half2* __restrict__ A1h2,
    float* __restrict__ chi, float* __restrict__ out) {
  __shared__ float s_wrt[256];
  __shared__ float s_e[EC*FW];
  __shared__ float s_tile[8*90];
  __shared__ float s_B[288];
  int bid = blockIdx.x;
  int n = bid >> 1, half = bid & 1;
  int t = threadIdx.x;
  s_wrt[t] = W_rt[t];
  int rq[2], kk[2], i0[2], c0[2], l0[2], i1[2], c1[2], l1[2], qg[2];
  bool val[2];
  #pragma unroll
  for (int jj = 0; jj < 2; ++jj) {
    int j = t + jj*256;
    val[jj] = (j < 360);
    int js = val[jj] ? j : 0;
    rq[jj] = js / 45; kk[jj] = js % 45;
    qg[jj] = rq[jj]*90 + kk[jj] + half*45;
    int rem0 = 2*(kk[jj] + 45*half);
    i0[jj] = rem0 / 9;  c0[jj] = rem0 % 9;  l0[jj] = c_LOF[i0[jj]];
    int rem1 = rem0 + 1;
    i1[jj] = rem1 / 9;  c1[jj] = rem1 % 9;  l1[jj] = c_LOF[i1[jj]];
  }
  float acc[2][2] = {{0,0},{0,0}};
  int beg = offsets[n], end = offsets[n+1];
  const float4* f4 = (const float4*)facS;
  for (int base = beg; base < end; base += EC) {
    int m = min(EC, end - base);
    __syncthreads();
    for (int idx = t; idx < m*(FW/4); idx += 256)
      ((float4*)s_e)[idx] = f4[(size_t)base*(FW/4) + idx];
    __syncthreads();
    for (int p = 0; p < m; ++p) {
      const float* e0 = s_e + p*FW;
      #pragma unroll
      for (int jj = 0; jj < 2; ++jj) {
        if (val[jj]) {
          float rv = e0[rq[jj]];
          acc[jj][0] += rv * e0[8+i0[jj]] * e0[28+c0[jj]];
          acc[jj][1] += rv * e0[8+i1[jj]] * e0[28+c1[jj]];
        }
      }
    }
  }
  __syncthreads();
  #pragma unroll
  for (int jj = 0; jj < 2; ++jj)
    if (val[jj]) {
      s_tile[rq[jj]*90 + 2*kk[jj]]     = acc[jj][0];
      s_tile[rq[jj]*90 + 2*kk[jj] + 1] = acc[jj][1];
    }
  __syncthreads();
  float a1v[2][2];
  #pragma unroll
  for (int jj = 0; jj < 2; ++jj) {
    if (val[jj]) {
      float ab0 = 0.f, ab1 = 0.f;
      #pragma unroll
      for (int r = 0; r < NRB; ++r) {
        ab0 += s_tile[r*90 + 2*kk[jj]]     * s_wrt[l0[jj]*64 + r*8 + rq[jj]];
        ab1 += s_tile[r*90 + 2*kk[jj] + 1] * s_wrt[l1[jj]*64 + r*8 + rq[jj]];
      }
      a1v[jj][0] = ab0; a1v[jj][1] = ab1;
      size_t qi = (size_t)n*NP2 + qg[jj];
      A1f2[qi] = make_float2(ab0, ab1);
      A1h2[qi] = __floats2half2_rn(ab0, ab1);
    }
  }
  __syncthreads();
  #pragma unroll
  for (int jj = 0; jj < 2; ++jj)
    if (val[jj]) {
      s_tile[rq[jj]*90 + 2*kk[jj]]     = a1v[jj][0];
      s_tile[rq[jj]*90 + 2*kk[jj] + 1] = a1v[jj][1];
    }
  __syncthreads();
  if (half == 0) {
    for (int m2 = t; m2 < 288; m2 += 256) {
      int s = m2 / 36, rm = m2 % 36, l5 = rm / 9, c = rm % 9;
      float b;
      if (l5 == 0) b = s_tile[s*90 + c];
      else {
        b = 0.f;
        for (int i = c_GB[l5]; i < c_GE[l5]; ++i) {
          float v = s_tile[s*90 + i*9 + c];
          b += c_PREF[i]*v*v;
        }
      }
      out[(size_t)(((n*8 + s)*5 + l5)*9 + c)*2 + 0] = b;
      s_B[m2] = b;
    }
    __syncthreads();
    if (t < 9) {
      float x = 0.f;
      #pragma unroll
      for (int u = 0; u < 32; ++u) x += s_B[u*9 + t];
      atomicAdd(&chi[n*9 + t], x);
    }
  } else {
    if (t < 72) {
      int s = t / 9, c = t % 9;
      float b = 0.f;
      for (int i = 10; i < 20; ++i) {
        float v = s_tile[s*90 + (i-10)*9 + c];
        b += c_PREF[i]*v*v;
      }
      out[(size_t)(((n*8 + s)*5 + 4)*9 + c)*2 + 0] = b;
      s_B[t] = b;
    }
    __syncthreads();
    if (t < 9) {
      float x = 0.f;
      #pragma unroll
      for (int u = 0; u < 8; ++u) x += s_B[u*9 + t];
      atomicAdd(&chi[n*9 + t], x);
    }
  }
}

__global__ __launch_bounds__(256, 4) void k_nodeMP(
    const float* __restrict__ facS, const int* __restrict__ offsets,
    const int* __restrict__ sndS,
    const float* __restrict__ W_rt, const float* __restrict__ W_nm,
    const float2* __restrict__ A1f2, const __half2* __restrict__ A1h2,
    const float* __restrict__ chi, float* __restrict__ out) {
  __shared__ float s_wrt[256];
  __shared__ float s_wnm[288];
  __shared__ float s_e[EC*FW];
  __shared__ float s_echi[EC*12];
  __shared__ int   s_snd[EC];
  __shared__ float s_tile[8*90];
  int bid = blockIdx.x;
  int n = bid >> 1, half = bid & 1;
  int t = threadIdx.x;
  s_wrt[t] = W_rt[t];
  s_wnm[t] = W_nm[t];
  if (t < 32) s_wnm[256 + t] = W_nm[256 + t];
  int rq[2], kk[2], i0[2], c0[2], l0[2], i1[2], c1[2], l1[2], qg[2];
  bool val[2];
  #pragma unroll
  for (int jj = 0; jj < 2; ++jj) {
    int j = t + jj*256;
    val[jj] = (j < 360);
    int js = val[jj] ? j : 0;
    rq[jj] = js / 45; kk[jj] = js % 45;
    qg[jj] = rq[jj]*90 + kk[jj] + half*45;
    int rem0 = 2*(kk[jj] + 45*half);
    i0[jj] = rem0 / 9;  c0[jj] = rem0 % 9;  l0[jj] = c_LOF[i0[jj]];
    int rem1 = rem0 + 1;
    i1[jj] = rem1 / 9;  c1[jj] = rem1 % 9;  l1[jj] = c_LOF[i1[jj]];
  }
  float accA[2][2] = {{0,0},{0,0}};
  float accB[2][2] = {{0,0},{0,0}};
  float2 mymem[2];
  #pragma unroll
  for (int jj = 0; jj < 2; ++jj)
    mymem[jj] = val[jj] ? A1f2[(size_t)n*NP2 + qg[jj]] : make_float2(0.f, 0.f);
  int beg = offsets[n], end = offsets[n+1];
  const float4* f4 = (const float4*)facS;
  for (int base = beg; base < end; base += EC) {
    int m = min(EC, end - base);
    __syncthreads();
    for (int idx = t; idx < m*(FW/4); idx += 256)
      ((float4*)s_e)[idx] = f4[(size_t)base*(FW/4) + idx];
    for (int idx = t; idx < m; idx += 256) s_snd[idx] = sndS[base + idx];
    __syncthreads();
    for (int idx = t; idx < m*9; idx += 256) {
      int p = idx / 9, c = idx - p*9;
      s_echi[p*12 + c] = chi[s_snd[p]*9 + c] * s_e[p*FW + 28 + c];
    }
    __syncthreads();
    int p = 0;
    for (; p + 3 < m; p += 4) {
      __half2 g[4][2];
      #pragma unroll
      for (int x = 0; x < 4; ++x) {
        const __half2* Ah = A1h2 + (size_t)s_snd[p+x]*NP2;
        g[x][0] = Ah[qg[0]];
        if (val[1]) g[x][1] = Ah[qg[1]];
      }
      #pragma unroll
      for (int x = 0; x < 4; ++x) {
        const float* e0 = s_e + (p+x)*FW;
        const float* x0 = s_echi + (p+x)*12;
        #pragma unroll
        for (int jj = 0; jj < 2; ++jj) {
          if (val[jj]) {
            float rv = e0[rq[jj]];
            float2 gf = __half22float2(g[x][jj]);
            accA[jj][0] += gf.x * rv;
            accA[jj][1] += gf.y * rv;
            accB[jj][0] += rv * e0[8+i0[jj]] * x0[c0[jj]];
            accB[jj][1] += rv * e0[8+i1[jj]] * x0[c1[jj]];
          }
        }
      }
    }
    for (; p < m; ++p) {
      const float* e0 = s_e + p*FW;
      const float* x0 = s_echi + p*12;
      const __half2* Ah = A1h2 + (size_t)s_snd[p]*NP2;
      #pragma unroll
      for (int jj = 0; jj < 2; ++jj) {
        if (val[jj]) {
          float rv = e0[rq[jj]];
          float2 gf = __half22float2(Ah[qg[jj]]);
          accA[jj][0] += gf.x * rv;
          accA[jj][1] += gf.y * rv;
          accB[jj][0] += rv * e0[8+i0[jj]] * x0[c0[jj]];
          accB[jj][1] += rv * e0[8+i1[jj]] * x0[c1[jj]];
        }
      }
    }
  }
  __syncthreads();
  #pragma unroll
  for (int jj = 0; jj < 2; ++jj)
    if (val[jj]) {
      s_tile[rq[jj]*90 + 2*kk[jj]]     = accB[jj][0];
      s_tile[rq[jj]*90 + 2*kk[jj] + 1] = accB[jj][1];
    }
  __syncthreads();
  float a2v[2][2];
  #pragma unroll
  for (int jj = 0; jj < 2; ++jj) {
    if (val[jj]) {
      float ab0 = 0.f, ab1 = 0.f;
      #pragma unroll
      for (int r = 0; r < NRB; ++r) {
        ab0 += s_tile[r*90 + 2*kk[jj]]     * s_wrt[l0[jj]*64 + r*8 + rq[jj]];
        ab1 += s_tile[r*90 + 2*kk[jj] + 1] * s_wrt[l1[jj]*64 + r*8 + rq[jj]];
      }
      float mem0 = mymem[jj].x * s_wnm[rq[jj]*36 + l0[jj]*9 + c0[jj]];
      float mem1 = mymem[jj].y * s_wnm[rq[jj]*36 + l1[jj]*9 + c1[jj]];
      a2v[jj][0] = (ab0 + accA[jj][0])*MPN + mem0;
      a2v[jj][1] = (ab1 + accA[jj][1])*MPN + mem1;
    }
  }
  __syncthreads();
  #pragma unroll
  for (int jj = 0; jj < 2; ++jj)
    if (val[jj]) {
      s_tile[rq[jj]*90 + 2*kk[jj]]     = a2v[jj][0];
      s_tile[rq[jj]*90 + 2*kk[jj] + 1] = a2v[jj][1];
    }
  __syncthreads();
  if (half == 0) {
    for (int m2 = t; m2 < 288; m2 += 256) {
      int s = m2 / 36, rm = m2 % 36, l5 = rm / 9, c = rm % 9;
      float b;
      if (l5 == 0) b = s_tile[s*90 + c];
      else {
        b = 0.f;
        for (int i = c_GB[l5]; i < c_GE[l5]; ++i) {
          float v = s_tile[s*90 + i*9 + c];
          b += c_PREF[i]*v*v;
        }
      }
      out[(size_t)(((n*8 + s)*5 + l5)*9 + c)*2 + 1] = b;
    }
  } else {
    if (t < 72) {
      int s = t / 9, c = t % 9;
      float b = 0.f;
      for (int i = 10; i < 20; ++i) {
        float v = s_tile[s*90 + (i-10)*9 + c];
        b += c_PREF[i]*v*v;
      }
      out[(size_t)(((n*8 + s)*5 + 4)*9 + c)*2 + 1] = b;
    }
  }
}

extern "C" void kernel_launch(void* const* d_in, const int* in_sizes, int n_in,
                              void* d_out, int out_size, void* d_ws, size_t ws_size,
                              hipStream_t stream) {
  const float* pos    = (const float*)d_in[0];
  const float* shifts = (const float*)d_in[1];
  const float* W_emb  = (const float*)d_in[2];
  const float* W_rt   = (const float*)d_in[3];
  const float* W_nm   = (const float*)d_in[4];
  const int*   an     = (const int*)d_in[5];
  const int*   ei     = (const int*)d_in[6];
  float* out = (float*)d_out;

  char* ws = (char*)d_ws;
  size_t off = 0;
  auto carve = [&](size_t bytes) {
    void* p = ws + off;
    off = (off + bytes + 255) & ~(size_t)255;
    return p;
  };
  float*   nemb    = (float*)carve((size_t)NNODE*3*sizeof(float));
  float*   facS    = (float*)carve((size_t)FW*NEDGE*sizeof(float));
  int*     sndS    = (int*)carve((size_t)NEDGE*sizeof(int));
  float2*  A1f2    = (float2*)carve((size_t)NNODE*NEL*sizeof(float));
  __half2* A1h2    = (__half2*)carve((size_t)NNODE*NEL*sizeof(__half));
  float*   chi     = (float*)carve((size_t)NNODE*NCH*sizeof(float));
  int*     counts  = (int*)carve((size_t)NNODE*sizeof(int));
  int*     offsets = (int*)carve((size_t)(NNODE+1)*sizeof(int));
  int*     cursor  = (int*)carve((size_t)NNODE*sizeof(int));

  hipMemsetAsync(counts, 0, (size_t)NNODE*sizeof(int), stream);
  hipMemsetAsync(chi, 0, (size_t)NNODE*NCH*sizeof(float), stream);
  k_emb<<<(NNODE+255)/256, 256, 0, stream>>>(an, W_emb, nemb);
  k_count<<<(NEDGE+255)/256, 256, 0, stream>>>(ei, counts);
  k_scan<<<1, 1024, 0, stream>>>(counts, offsets, cursor);
  k_edgec<<<(NEDGE+255)/256, 256, 0, stream>>>(pos, shifts, ei, nemb, cursor, facS, sndS);
  k_nodeA<<<NNODE*2, 256, 0, stream>>>(facS, offsets, W_rt, A1f2, A1h2, chi, out);
  k_nodeMP<<<NNODE*2, 256, 0, stream>>>(facS, offsets, sndS, W_rt, W_nm, A1f2, A1h2, chi, out);
}

// Round 8
// 131.477 us; speedup vs baseline: 1.6410x; 1.0104x over previous
//
#include <hip/hip_runtime.h>
#include <hip/hip_fp16.h>

#ifndef M_PIf
#define M_PIf 3.14159265358979323846f
#endif

constexpr int NNODE = 4000;
constexpr int NEDGE = 48000;
constexpr int NLA   = 20;                 // angular terms
constexpr int NCH   = 9;                  // channels
constexpr int NRB   = 8;                  // radial basis / transformed
constexpr int NEL   = NRB * NLA * NCH;    // 1440 elements per node tensor
constexpr int NP2   = NEL / 2;            // 720 half2 pairs
constexpr int FW    = 40;                 // padded per-edge factor width
constexpr int EC    = 32;                 // edge chunk per LDS stage
constexpr int PF    = 16;                 // gather prefetch depth (edges)
constexpr float CUT = 5.5f;
constexpr float MPN = 0.316227766016837933f;  // 1/sqrt(10)

__constant__ int   c_LOF[NLA]  = {0,1,1,1,2,2,2,2,2,2,3,3,3,3,3,3,3,3,3,3};
__constant__ float c_PREF[NLA] = {1,1,1,1,1,2,2,1,2,1,1,3,3,3,6,3,1,3,3,1};
__constant__ int   c_GB[4] = {0,0,1,4};   // groups for l5=0..3 (half 0)
__constant__ int   c_GE[4] = {0,1,4,10};

__global__ void k_count(const int* __restrict__ ei, int* __restrict__ counts) {
  int e = blockIdx.x * blockDim.x + threadIdx.x;
  if (e >= NEDGE) return;
  atomicAdd(&counts[ei[NEDGE + e]], 1);
}

__global__ void k_scan(const int* __restrict__ counts, int* __restrict__ offsets,
                       int* __restrict__ cursor) {
  __shared__ int lds[1024];
  int t = threadIdx.x;
  int base = t*4;
  int c0 = (base+0 < NNODE) ? counts[base+0] : 0;
  int c1 = (base+1 < NNODE) ? counts[base+1] : 0;
  int c2 = (base+2 < NNODE) ? counts[base+2] : 0;
  int c3 = (base+3 < NNODE) ? counts[base+3] : 0;
  lds[t] = c0+c1+c2+c3;
  __syncthreads();
  for (int d = 1; d < 1024; d <<= 1) {
    int v = (t >= d) ? lds[t-d] : 0;
    __syncthreads();
    lds[t] += v;
    __syncthreads();
  }
  int excl = (t == 0) ? 0 : lds[t-1];
  int o0 = excl, o1 = o0+c0, o2 = o1+c1, o3 = o2+c2;
  if (base+0 < NNODE) { offsets[base+0]=o0; cursor[base+0]=o0; }
  if (base+1 < NNODE) { offsets[base+1]=o1; cursor[base+1]=o1; }
  if (base+2 < NNODE) { offsets[base+2]=o2; cursor[base+2]=o2; }
  if (base+3 < NNODE) { offsets[base+3]=o3; cursor[base+3]=o3; }
  if (t == 1023) offsets[NNODE] = lds[1023];
}

// Factors in CSR order, edge-major: facS[p][0..7]=rc, [8..27]=ang, [28..36]=enc
// (k_emb folded in: species lookup + W_emb read inline)
__global__ void k_edgec(const float* __restrict__ pos, const float* __restrict__ shifts,
                        const int* __restrict__ ei, const int* __restrict__ an,
                        const float* __restrict__ W_emb,
                        int* __restrict__ cursor, float* __restrict__ facS,
                        int* __restrict__ sndS) {
  int e = blockIdx.x * blockDim.x + threadIdx.x;
  if (e >= NEDGE) return;
  int snd = ei[e];
  int rcv = ei[NEDGE + e];
  float vx = pos[rcv*3+0] - pos[snd*3+0] + shifts[e*3+0];
  float vy = pos[rcv*3+1] - pos[snd*3+1] + shifts[e*3+1];
  float vz = pos[rcv*3+2] - pos[snd*3+2] + shifts[e*3+2];
  float len = sqrtf(vx*vx + vy*vy + vz*vz);
  float inv = 1.0f / len;
  float x = vx*inv, y = vy*inv, z = vz*inv;
  float u  = len * (1.0f/CUT);
  float u2 = u*u;
  float u6 = u2*u2*u2;
  float fcut = 1.0f - 28.0f*u6 + 48.0f*u6*u - 21.0f*u6*u2;
  if (u >= 1.0f) fcut = 0.0f;
  float pre = sqrtf(2.0f/CUT) * fcut * inv;
  int p = atomicAdd(&cursor[rcv], 1);
  float* f = facS + (size_t)p*FW;
  #pragma unroll
  for (int j = 0; j < NRB; ++j)
    f[j] = pre * sinf((float)(j+1) * M_PIf * u);
  float ang[NLA];
  ang[0]=1.0f; ang[1]=x; ang[2]=y; ang[3]=z;
  ang[4]=x*x; ang[5]=x*y; ang[6]=x*z; ang[7]=y*y; ang[8]=y*z; ang[9]=z*z;
  ang[10]=ang[4]*x; ang[11]=ang[4]*y; ang[12]=ang[4]*z;
  ang[13]=x*ang[7]; ang[14]=ang[5]*z; ang[15]=x*ang[9];
  ang[16]=ang[7]*y; ang[17]=ang[7]*z; ang[18]=y*ang[9]; ang[19]=ang[9]*z;
  #pragma unroll
  for (int i = 0; i < NLA; ++i) f[8+i] = ang[i];
  int as_ = an[snd], ar_ = an[rcv];
  int sps = (as_==1)?0:(as_==6)?1:(as_==7)?2:3;
  int spr = (ar_==1)?0:(ar_==6)?1:(ar_==7)?2:3;
  float es0=W_emb[sps*3+0], es1=W_emb[sps*3+1], es2=W_emb[sps*3+2];
  float er0=W_emb[spr*3+0], er1=W_emb[spr*3+1], er2=W_emb[spr*3+2];
  f[28]=es0*er0; f[29]=es0*er1; f[30]=es0*er2;
  f[31]=es1*er0; f[32]=es1*er1; f[33]=es1*er2;
  f[34]=es2*er0; f[35]=es2*er1; f[36]=es2*er2;
  f[37]=0.f; f[38]=0.f; f[39]=0.f;
  sndS[p] = snd;
}

// ---- split-node kernels: block = (node, half); half owns i in [10*half, 10*half+10)
// pair slot j in [0,360): r_out = j/45, kk = j%45; global half2-pair q = r_out*90+kk+45*half

__global__ __launch_bounds__(256, 4) void k_nodeA(
    const float* __restrict__ facS, const int* __restrict__ offsets,
    const float* __restrict__ W_rt,
    float2* __restrict__ A1f2, __half2* __restrict__ A1h2,
    float* __restrict__ chi, float* __restrict__ out) {
  __shared__ float s_wrt[256];
  __shared__ float s_e[EC*FW];
  __shared__ float s_tile[8*90];
  __shared__ float s_B[288];
  int bid = blockIdx.x;
  int n = bid >> 1, half = bid & 1;
  int t = threadIdx.x;
  s_wrt[t] = W_rt[t];
  int rq[2], kk[2], i0[2], c0[2], l0[2], i1[2], c1[2], l1[2], qg[2];
  bool val[2];
  #pragma unroll
  for (int jj = 0; jj < 2; ++jj) {
    int j = t + jj*256;
    val[jj] = (j < 360);
    int js = val[jj] ? j : 0;
    rq[jj] = js / 45; kk[jj] = js % 45;
    qg[jj] = rq[jj]*90 + kk[jj] + half*45;
    int rem0 = 2*(kk[jj] + 45*half);
    i0[jj] = rem0 / 9;  c0[jj] = rem0 % 9;  l0[jj] = c_LOF[i0[jj]];
    int rem1 = rem0 + 1;
    i1[jj] = rem1 / 9;  c1[jj] = rem1 % 9;  l1[jj] = c_LOF[i1[jj]];
  }
  float acc[2][2] = {{0,0},{0,0}};
  int beg = offsets[n], end = offsets[n+1];
  const float4* f4 = (const float4*)facS;
  for (int base = beg; base < end; base += EC) {
    int m = min(EC, end - base);
    __syncthreads();
    for (int idx = t; idx < m*(FW/4); idx += 256)
      ((float4*)s_e)[idx] = f4[(size_t)base*(FW/4) + idx];
    __syncthreads();
    for (int p = 0; p < m; ++p) {
      const float* e0 = s_e + p*FW;
      #pragma unroll
      for (int jj = 0; jj < 2; ++jj) {
        if (val[jj]) {
          float rv = e0[rq[jj]];
          acc[jj][0] += rv * e0[8+i0[jj]] * e0[28+c0[jj]];
          acc[jj][1] += rv * e0[8+i1[jj]] * e0[28+c1[jj]];
        }
      }
    }
  }
  __syncthreads();
  #pragma unroll
  for (int jj = 0; jj < 2; ++jj)
    if (val[jj]) {
      s_tile[rq[jj]*90 + 2*kk[jj]]     = acc[jj][0];
      s_tile[rq[jj]*90 + 2*kk[jj] + 1] = acc[jj][1];
    }
  __syncthreads();
  float a1v[2][2];
  #pragma unroll
  for (int jj = 0; jj < 2; ++jj) {
    if (val[jj]) {
      float ab0 = 0.f, ab1 = 0.f;
      #pragma unroll
      for (int r = 0; r < NRB; ++r) {
        ab0 += s_tile[r*90 + 2*kk[jj]]     * s_wrt[l0[jj]*64 + r*8 + rq[jj]];
        ab1 += s_tile[r*90 + 2*kk[jj] + 1] * s_wrt[l1[jj]*64 + r*8 + rq[jj]];
      }
      a1v[jj][0] = ab0; a1v[jj][1] = ab1;
      size_t qi = (size_t)n*NP2 + qg[jj];
      A1f2[qi] = make_float2(ab0, ab1);
      A1h2[qi] = __floats2half2_rn(ab0, ab1);
    }
  }
  __syncthreads();
  #pragma unroll
  for (int jj = 0; jj < 2; ++jj)
    if (val[jj]) {
      s_tile[rq[jj]*90 + 2*kk[jj]]     = a1v[jj][0];
      s_tile[rq[jj]*90 + 2*kk[jj] + 1] = a1v[jj][1];
    }
  __syncthreads();
  if (half == 0) {
    for (int m2 = t; m2 < 288; m2 += 256) {
      int s = m2 / 36, rm = m2 % 36, l5 = rm / 9, c = rm % 9;
      float b;
      if (l5 == 0) b = s_tile[s*90 + c];
      else {
        b = 0.f;
        for (int i = c_GB[l5]; i < c_GE[l5]; ++i) {
          float v = s_tile[s*90 + i*9 + c];
          b += c_PREF[i]*v*v;
        }
      }
      out[(size_t)(((n*8 + s)*5 + l5)*9 + c)*2 + 0] = b;
      s_B[m2] = b;
    }
    __syncthreads();
    if (t < 9) {
      float x = 0.f;
      #pragma unroll
      for (int u = 0; u < 32; ++u) x += s_B[u*9 + t];
      atomicAdd(&chi[n*9 + t], x);
    }
  } else {
    if (t < 72) {
      int s = t / 9, c = t % 9;
      float b = 0.f;
      for (int i = 10; i < 20; ++i) {
        float v = s_tile[s*90 + (i-10)*9 + c];
        b += c_PREF[i]*v*v;
      }
      out[(size_t)(((n*8 + s)*5 + 4)*9 + c)*2 + 0] = b;
      s_B[t] = b;
    }
    __syncthreads();
    if (t < 9) {
      float x = 0.f;
      #pragma unroll
      for (int u = 0; u < 8; ++u) x += s_B[u*9 + t];
      atomicAdd(&chi[n*9 + t], x);
    }
  }
}

__global__ __launch_bounds__(256, 4) void k_nodeMP(
    const float* __restrict__ facS, const int* __restrict__ offsets,
    const int* __restrict__ sndS,
    const float* __restrict__ W_rt, const float* __restrict__ W_nm,
    const float2* __restrict__ A1f2, const __half2* __restrict__ A1h2,
    const float* __restrict__ chi, float* __restrict__ out) {
  __shared__ float s_wrt[256];
  __shared__ float s_wnm[288];
  __shared__ float s_e[EC*FW];
  __shared__ float s_echi[EC*12];
  __shared__ int   s_snd[EC];
  __shared__ float s_tile[8*90];
  int bid = blockIdx.x;
  int n = bid >> 1, half = bid & 1;
  int t = threadIdx.x;
  s_wrt[t] = W_rt[t];
  s_wnm[t] = W_nm[t];
  if (t < 32) s_wnm[256 + t] = W_nm[256 + t];
  int rq[2], kk[2], i0[2], c0[2], l0[2], i1[2], c1[2], l1[2], qg[2];
  bool val[2];
  #pragma unroll
  for (int jj = 0; jj < 2; ++jj) {
    int j = t + jj*256;
    val[jj] = (j < 360);
    int js = val[jj] ? j : 0;
    rq[jj] = js / 45; kk[jj] = js % 45;
    qg[jj] = rq[jj]*90 + kk[jj] + half*45;
    int rem0 = 2*(kk[jj] + 45*half);
    i0[jj] = rem0 / 9;  c0[jj] = rem0 % 9;  l0[jj] = c_LOF[i0[jj]];
    int rem1 = rem0 + 1;
    i1[jj] = rem1 / 9;  c1[jj] = rem1 % 9;  l1[jj] = c_LOF[i1[jj]];
  }
  float accA[2][2] = {{0,0},{0,0}};
  float accB[2][2] = {{0,0},{0,0}};
  float2 mymem[2];
  #pragma unroll
  for (int jj = 0; jj < 2; ++jj)
    mymem[jj] = val[jj] ? A1f2[(size_t)n*NP2 + qg[jj]] : make_float2(0.f, 0.f);
  int beg = offsets[n], end = offsets[n+1];
  const float4* f4 = (const float4*)facS;
  for (int base = beg; base < end; base += EC) {
    int m = min(EC, end - base);
    __syncthreads();
    for (int idx = t; idx < m*(FW/4); idx += 256)
      ((float4*)s_e)[idx] = f4[(size_t)base*(FW/4) + idx];
    for (int idx = t; idx < m; idx += 256) s_snd[idx] = sndS[base + idx];
    __syncthreads();
    for (int idx = t; idx < m*9; idx += 256) {
      int p = idx / 9, c = idx - p*9;
      s_echi[p*12 + c] = chi[s_snd[p]*9 + c] * s_e[p*FW + 28 + c];
    }
    __syncthreads();
    // deep-prefetch groups: issue all PF edges' gathers, then consume
    for (int g0 = 0; g0 < m; g0 += PF) {
      int gm = min(PF, m - g0);     // block-uniform
      __half2 ga[PF], gb[PF];
      #pragma unroll
      for (int x = 0; x < PF; ++x) {
        int pp = g0 + ((x < gm) ? x : (gm - 1));
        const __half2* Ah = A1h2 + (size_t)s_snd[pp]*NP2;
        ga[x] = Ah[qg[0]];
        if (val[1]) gb[x] = Ah[qg[1]];
      }
      #pragma unroll
      for (int x = 0; x < PF; ++x) {
        if (x < gm) {
          const float* e0 = s_e + (g0+x)*FW;
          const float* x0 = s_echi + (g0+x)*12;
          {
            float rv = e0[rq[0]];
            float2 gf = __half22float2(ga[x]);
            accA[0][0] += gf.x * rv;
            accA[0][1] += gf.y * rv;
            accB[0][0] += rv * e0[8+i0[0]] * x0[c0[0]];
            accB[0][1] += rv * e0[8+i1[0]] * x0[c1[0]];
          }
          if (val[1]) {
            float rv = e0[rq[1]];
            float2 gf = __half22float2(gb[x]);
            accA[1][0] += gf.x * rv;
            accA[1][1] += gf.y * rv;
            accB[1][0] += rv * e0[8+i0[1]] * x0[c0[1]];
            accB[1][1] += rv * e0[8+i1[1]] * x0[c1[1]];
          }
        }
      }
    }
  }
  __syncthreads();
  #pragma unroll
  for (int jj = 0; jj < 2; ++jj)
    if (val[jj]) {
      s_tile[rq[jj]*90 + 2*kk[jj]]     = accB[jj][0];
      s_tile[rq[jj]*90 + 2*kk[jj] + 1] = accB[jj][1];
    }
  __syncthreads();
  float a2v[2][2];
  #pragma unroll
  for (int jj = 0; jj < 2; ++jj) {
    if (val[jj]) {
      float ab0 = 0.f, ab1 = 0.f;
      #pragma unroll
      for (int r = 0; r < NRB; ++r) {
        ab0 += s_tile[r*90 + 2*kk[jj]]     * s_wrt[l0[jj]*64 + r*8 + rq[jj]];
        ab1 += s_tile[r*90 + 2*kk[jj] + 1] * s_wrt[l1[jj]*64 + r*8 + rq[jj]];
      }
      float mem0 = mymem[jj].x * s_wnm[rq[jj]*36 + l0[jj]*9 + c0[jj]];
      float mem1 = mymem[jj].y * s_wnm[rq[jj]*36 + l1[jj]*9 + c1[jj]];
      a2v[jj][0] = (ab0 + accA[jj][0])*MPN + mem0;
      a2v[jj][1] = (ab1 + accA[jj][1])*MPN + mem1;
    }
  }
  __syncthreads();
  #pragma unroll
  for (int jj = 0; jj < 2; ++jj)
    if (val[jj]) {
      s_tile[rq[jj]*90 + 2*kk[jj]]     = a2v[jj][0];
      s_tile[rq[jj]*90 + 2*kk[jj] + 1] = a2v[jj][1];
    }
  __syncthreads();
  if (half == 0) {
    for (int m2 = t; m2 < 288; m2 += 256) {
      int s = m2 / 36, rm = m2 % 36, l5 = rm / 9, c = rm % 9;
      float b;
      if (l5 == 0) b = s_tile[s*90 + c];
      else {
        b = 0.f;
        for (int i = c_GB[l5]; i < c_GE[l5]; ++i) {
          float v = s_tile[s*90 + i*9 + c];
          b += c_PREF[i]*v*v;
        }
      }
      out[(size_t)(((n*8 + s)*5 + l5)*9 + c)*2 + 1] = b;
    }
  } else {
    if (t < 72) {
      int s = t / 9, c = t % 9;
      float b = 0.f;
      for (int i = 10; i < 20; ++i) {
        float v = s_tile[s*90 + (i-10)*9 + c];
        b += c_PREF[i]*v*v;
      }
      out[(size_t)(((n*8 + s)*5 + 4)*9 + c)*2 + 1] = b;
    }
  }
}

extern "C" void kernel_launch(void* const* d_in, const int* in_sizes, int n_in,
                              void* d_out, int out_size, void* d_ws, size_t ws_size,
                              hipStream_t stream) {
  const float* pos    = (const float*)d_in[0];
  const float* shifts = (const float*)d_in[1];
  const float* W_emb  = (const float*)d_in[2];
  const float* W_rt   = (const float*)d_in[3];
  const float* W_nm   = (const float*)d_in[4];
  const int*   an     = (const int*)d_in[5];
  const int*   ei     = (const int*)d_in[6];
  float* out = (float*)d_out;

  char* ws = (char*)d_ws;
  size_t off = 0;
  auto carve = [&](size_t bytes) {
    void* p = ws + off;
    off = (off + bytes + 255) & ~(size_t)255;
    return p;
  };
  float*   facS    = (float*)carve((size_t)FW*NEDGE*sizeof(float));
  int*     sndS    = (int*)carve((size_t)NEDGE*sizeof(int));
  float2*  A1f2    = (float2*)carve((size_t)NNODE*NEL*sizeof(float));
  __half2* A1h2    = (__half2*)carve((size_t)NNODE*NEL*sizeof(__half));
  float*   chi     = (float*)carve((size_t)NNODE*NCH*sizeof(float));
  int*     counts  = (int*)carve((size_t)NNODE*sizeof(int));
  int*     offsets = (int*)carve((size_t)(NNODE+1)*sizeof(int));
  int*     cursor  = (int*)carve((size_t)NNODE*sizeof(int));

  // one memset covers chi..counts (adjacent carves)
  size_t z0 = (size_t)((char*)chi - ws);
  size_t z1 = (size_t)((char*)counts - ws) + (size_t)NNODE*sizeof(int);
  hipMemsetAsync((char*)ws + z0, 0, z1 - z0, stream);
  k_count<<<(NEDGE+255)/256, 256, 0, stream>>>(ei, counts);
  k_scan<<<1, 1024, 0, stream>>>(counts, offsets, cursor);
  k_edgec<<<(NEDGE+255)/256, 256, 0, stream>>>(pos, shifts, ei, an, W_emb, cursor, facS, sndS);
  k_nodeA<<<NNODE*2, 256, 0, stream>>>(facS, offsets, W_rt, A1f2, A1h2, chi, out);
  k_nodeMP<<<NNODE*2, 256, 0, stream>>>(facS, offsets, sndS, W_rt, W_nm, A1f2, A1h2, chi, out);
}

// Round 9
// 122.082 us; speedup vs baseline: 1.7673x; 1.0770x over previous
//
#include <hip/hip_runtime.h>
#include <hip/hip_fp16.h>

#ifndef M_PIf
#define M_PIf 3.14159265358979323846f
#endif

constexpr int NNODE = 4000;
constexpr int NEDGE = 48000;
constexpr int NLA   = 20;                 // angular terms
constexpr int NCH   = 9;                  // channels
constexpr int NRB   = 8;                  // radial basis / transformed
constexpr int NEL   = NRB * NLA * NCH;    // 1440 elements per node tensor
constexpr int NP2   = NEL / 2;            // 720 half2 pairs
constexpr int FW    = 40;                 // padded per-edge factor width
constexpr int EC    = 32;                 // edge chunk per LDS stage
constexpr float CUT = 5.5f;
constexpr float MPN = 0.316227766016837933f;  // 1/sqrt(10)

__constant__ int   c_LOF[NLA]  = {0,1,1,1,2,2,2,2,2,2,3,3,3,3,3,3,3,3,3,3};
__constant__ float c_PREF[NLA] = {1,1,1,1,1,2,2,1,2,1,1,3,3,3,6,3,1,3,3,1};
__constant__ int   c_GB[4] = {0,0,1,4};   // groups for l5=0..3 (half 0)
__constant__ int   c_GE[4] = {0,1,4,10};

__global__ void k_count(const int* __restrict__ ei, int* __restrict__ counts) {
  int e = blockIdx.x * blockDim.x + threadIdx.x;
  if (e >= NEDGE) return;
  atomicAdd(&counts[ei[NEDGE + e]], 1);
}

__global__ void k_scan(const int* __restrict__ counts, int* __restrict__ offsets,
                       int* __restrict__ cursor) {
  __shared__ int lds[1024];
  int t = threadIdx.x;
  int base = t*4;
  int c0 = (base+0 < NNODE) ? counts[base+0] : 0;
  int c1 = (base+1 < NNODE) ? counts[base+1] : 0;
  int c2 = (base+2 < NNODE) ? counts[base+2] : 0;
  int c3 = (base+3 < NNODE) ? counts[base+3] : 0;
  lds[t] = c0+c1+c2+c3;
  __syncthreads();
  for (int d = 1; d < 1024; d <<= 1) {
    int v = (t >= d) ? lds[t-d] : 0;
    __syncthreads();
    lds[t] += v;
    __syncthreads();
  }
  int excl = (t == 0) ? 0 : lds[t-1];
  int o0 = excl, o1 = o0+c0, o2 = o1+c1, o3 = o2+c2;
  if (base+0 < NNODE) { offsets[base+0]=o0; cursor[base+0]=o0; }
  if (base+1 < NNODE) { offsets[base+1]=o1; cursor[base+1]=o1; }
  if (base+2 < NNODE) { offsets[base+2]=o2; cursor[base+2]=o2; }
  if (base+3 < NNODE) { offsets[base+3]=o3; cursor[base+3]=o3; }
  if (t == 1023) offsets[NNODE] = lds[1023];
}

// Factors in CSR order, edge-major: facS[p][0..7]=rc, [8..27]=ang, [28..36]=enc
__global__ void k_edgec(const float* __restrict__ pos, const float* __restrict__ shifts,
                        const int* __restrict__ ei, const int* __restrict__ an,
                        const float* __restrict__ W_emb,
                        int* __restrict__ cursor, float* __restrict__ facS,
                        int* __restrict__ sndS) {
  int e = blockIdx.x * blockDim.x + threadIdx.x;
  if (e >= NEDGE) return;
  int snd = ei[e];
  int rcv = ei[NEDGE + e];
  float vx = pos[rcv*3+0] - pos[snd*3+0] + shifts[e*3+0];
  float vy = pos[rcv*3+1] - pos[snd*3+1] + shifts[e*3+1];
  float vz = pos[rcv*3+2] - pos[snd*3+2] + shifts[e*3+2];
  float len = sqrtf(vx*vx + vy*vy + vz*vz);
  float inv = 1.0f / len;
  float x = vx*inv, y = vy*inv, z = vz*inv;
  float u  = len * (1.0f/CUT);
  float u2 = u*u;
  float u6 = u2*u2*u2;
  float fcut = 1.0f - 28.0f*u6 + 48.0f*u6*u - 21.0f*u6*u2;
  if (u >= 1.0f) fcut = 0.0f;
  float pre = sqrtf(2.0f/CUT) * fcut * inv;
  int p = atomicAdd(&cursor[rcv], 1);
  float* f = facS + (size_t)p*FW;
  #pragma unroll
  for (int j = 0; j < NRB; ++j)
    f[j] = pre * sinf((float)(j+1) * M_PIf * u);
  float ang[NLA];
  ang[0]=1.0f; ang[1]=x; ang[2]=y; ang[3]=z;
  ang[4]=x*x; ang[5]=x*y; ang[6]=x*z; ang[7]=y*y; ang[8]=y*z; ang[9]=z*z;
  ang[10]=ang[4]*x; ang[11]=ang[4]*y; ang[12]=ang[4]*z;
  ang[13]=x*ang[7]; ang[14]=ang[5]*z; ang[15]=x*ang[9];
  ang[16]=ang[7]*y; ang[17]=ang[7]*z; ang[18]=y*ang[9]; ang[19]=ang[9]*z;
  #pragma unroll
  for (int i = 0; i < NLA; ++i) f[8+i] = ang[i];
  int as_ = an[snd], ar_ = an[rcv];
  int sps = (as_==1)?0:(as_==6)?1:(as_==7)?2:3;
  int spr = (ar_==1)?0:(ar_==6)?1:(ar_==7)?2:3;
  float es0=W_emb[sps*3+0], es1=W_emb[sps*3+1], es2=W_emb[sps*3+2];
  float er0=W_emb[spr*3+0], er1=W_emb[spr*3+1], er2=W_emb[spr*3+2];
  f[28]=es0*er0; f[29]=es0*er1; f[30]=es0*er2;
  f[31]=es1*er0; f[32]=es1*er1; f[33]=es1*er2;
  f[34]=es2*er0; f[35]=es2*er1; f[36]=es2*er2;
  f[37]=0.f; f[38]=0.f; f[39]=0.f;
  sndS[p] = snd;
}

// echiS[p][c] = chi[snd_p][c] * enc_p[c]  (padded to 12 floats)
__global__ void k_echi(const float* __restrict__ facS, const int* __restrict__ sndS,
                       const float* __restrict__ chi, float* __restrict__ echiS) {
  int p = blockIdx.x * blockDim.x + threadIdx.x;
  if (p >= NEDGE) return;
  int snd = sndS[p];
  const float* f = facS + (size_t)p*FW;
  float* o = echiS + (size_t)p*12;
  #pragma unroll
  for (int c = 0; c < 9; ++c)
    o[c] = chi[snd*9 + c] * f[28 + c];
  o[9] = 0.f; o[10] = 0.f; o[11] = 0.f;
}

// ---- split-node kernels: block = (node, half); half owns i in [10*half, 10*half+10)
// pair slot j in [0,360): r_out = j/45, kk = j%45; global half2-pair q = r_out*90+kk+45*half

__global__ __launch_bounds__(256, 8) void k_nodeA(
    const float* __restrict__ facS, const int* __restrict__ offsets,
    const float* __restrict__ W_rt,
    float2* __restrict__ A1f2, __half2* __restrict__ A1h2,
    float* __restrict__ chi, float* __restrict__ out) {
  __shared__ float s_wrt[256];
  __shared__ float s_e[EC*FW];
  __shared__ float s_tile[8*90];
  __shared__ float s_B[288];
  int bid = blockIdx.x;
  int n = bid >> 1, half = bid & 1;
  int t = threadIdx.x;
  s_wrt[t] = W_rt[t];
  int rq[2], kk[2], i0[2], c0[2], l0[2], i1[2], c1[2], l1[2], qg[2];
  bool val[2];
  #pragma unroll
  for (int jj = 0; jj < 2; ++jj) {
    int j = t + jj*256;
    val[jj] = (j < 360);
    int js = val[jj] ? j : 0;
    rq[jj] = js / 45; kk[jj] = js % 45;
    qg[jj] = rq[jj]*90 + kk[jj] + half*45;
    int rem0 = 2*(kk[jj] + 45*half);
    i0[jj] = rem0 / 9;  c0[jj] = rem0 % 9;  l0[jj] = c_LOF[i0[jj]];
    int rem1 = rem0 + 1;
    i1[jj] = rem1 / 9;  c1[jj] = rem1 % 9;  l1[jj] = c_LOF[i1[jj]];
  }
  float acc[2][2] = {{0,0},{0,0}};
  int beg = offsets[n], end = offsets[n+1];
  const float4* f4 = (const float4*)facS;
  for (int base = beg; base < end; base += EC) {
    int m = min(EC, end - base);
    __syncthreads();
    for (int idx = t; idx < m*(FW/4); idx += 256)
      ((float4*)s_e)[idx] = f4[(size_t)base*(FW/4) + idx];
    __syncthreads();
    for (int p = 0; p < m; ++p) {
      const float* e0 = s_e + p*FW;
      #pragma unroll
      for (int jj = 0; jj < 2; ++jj) {
        if (val[jj]) {
          float rv = e0[rq[jj]];
          acc[jj][0] += rv * e0[8+i0[jj]] * e0[28+c0[jj]];
          acc[jj][1] += rv * e0[8+i1[jj]] * e0[28+c1[jj]];
        }
      }
    }
  }
  __syncthreads();
  #pragma unroll
  for (int jj = 0; jj < 2; ++jj)
    if (val[jj]) {
      s_tile[rq[jj]*90 + 2*kk[jj]]     = acc[jj][0];
      s_tile[rq[jj]*90 + 2*kk[jj] + 1] = acc[jj][1];
    }
  __syncthreads();
  float a1v[2][2];
  #pragma unroll
  for (int jj = 0; jj < 2; ++jj) {
    if (val[jj]) {
      float ab0 = 0.f, ab1 = 0.f;
      #pragma unroll
      for (int r = 0; r < NRB; ++r) {
        ab0 += s_tile[r*90 + 2*kk[jj]]     * s_wrt[l0[jj]*64 + r*8 + rq[jj]];
        ab1 += s_tile[r*90 + 2*kk[jj] + 1] * s_wrt[l1[jj]*64 + r*8 + rq[jj]];
      }
      a1v[jj][0] = ab0; a1v[jj][1] = ab1;
      size_t qi = (size_t)n*NP2 + qg[jj];
      A1f2[qi] = make_float2(ab0, ab1);
      A1h2[qi] = __floats2half2_rn(ab0, ab1);
    }
  }
  __syncthreads();
  #pragma unroll
  for (int jj = 0; jj < 2; ++jj)
    if (val[jj]) {
      s_tile[rq[jj]*90 + 2*kk[jj]]     = a1v[jj][0];
      s_tile[rq[jj]*90 + 2*kk[jj] + 1] = a1v[jj][1];
    }
  __syncthreads();
  if (half == 0) {
    for (int m2 = t; m2 < 288; m2 += 256) {
      int s = m2 / 36, rm = m2 % 36, l5 = rm / 9, c = rm % 9;
      float b;
      if (l5 == 0) b = s_tile[s*90 + c];
      else {
        b = 0.f;
        for (int i = c_GB[l5]; i < c_GE[l5]; ++i) {
          float v = s_tile[s*90 + i*9 + c];
          b += c_PREF[i]*v*v;
        }
      }
      out[(size_t)(((n*8 + s)*5 + l5)*9 + c)*2 + 0] = b;
      s_B[m2] = b;
    }
    __syncthreads();
    if (t < 9) {
      float x = 0.f;
      #pragma unroll
      for (int u = 0; u < 32; ++u) x += s_B[u*9 + t];
      atomicAdd(&chi[n*9 + t], x);
    }
  } else {
    if (t < 72) {
      int s = t / 9, c = t % 9;
      float b = 0.f;
      for (int i = 10; i < 20; ++i) {
        float v = s_tile[s*90 + (i-10)*9 + c];
        b += c_PREF[i]*v*v;
      }
      out[(size_t)(((n*8 + s)*5 + 4)*9 + c)*2 + 0] = b;
      s_B[t] = b;
    }
    __syncthreads();
    if (t < 9) {
      float x = 0.f;
      #pragma unroll
      for (int u = 0; u < 8; ++u) x += s_B[u*9 + t];
      atomicAdd(&chi[n*9 + t], x);
    }
  }
}

__global__ __launch_bounds__(256, 8) void k_nodeMP(
    const float* __restrict__ facS, const int* __restrict__ offsets,
    const int* __restrict__ sndS, const float* __restrict__ echiS,
    const float* __restrict__ W_rt, const float* __restrict__ W_nm,
    const float2* __restrict__ A1f2, const __half2* __restrict__ A1h2,
    float* __restrict__ out) {
  __shared__ float s_wrt[256];
  __shared__ float s_wnm[288];
  __shared__ float s_e[EC*FW];
  __shared__ float s_ec[EC*12];
  __shared__ float s_tile[8*90];
  int bid = blockIdx.x;
  int n = bid >> 1, half = bid & 1;
  int t = threadIdx.x;
  s_wrt[t] = W_rt[t];
  s_wnm[t] = W_nm[t];
  if (t < 32) s_wnm[256 + t] = W_nm[256 + t];
  int rq[2], kk[2], i0[2], c0[2], l0[2], i1[2], c1[2], l1[2], qg[2];
  bool val[2];
  #pragma unroll
  for (int jj = 0; jj < 2; ++jj) {
    int j = t + jj*256;
    val[jj] = (j < 360);
    int js = val[jj] ? j : 0;
    rq[jj] = js / 45; kk[jj] = js % 45;
    qg[jj] = rq[jj]*90 + kk[jj] + half*45;
    int rem0 = 2*(kk[jj] + 45*half);
    i0[jj] = rem0 / 9;  c0[jj] = rem0 % 9;  l0[jj] = c_LOF[i0[jj]];
    int rem1 = rem0 + 1;
    i1[jj] = rem1 / 9;  c1[jj] = rem1 % 9;  l1[jj] = c_LOF[i1[jj]];
  }
  float accA[2][2] = {{0,0},{0,0}};
  float accB[2][2] = {{0,0},{0,0}};
  float2 mymem[2];
  #pragma unroll
  for (int jj = 0; jj < 2; ++jj)
    mymem[jj] = val[jj] ? A1f2[(size_t)n*NP2 + qg[jj]] : make_float2(0.f, 0.f);
  int beg = offsets[n], end = offsets[n+1];
  const float4* f4 = (const float4*)facS;
  const float4* e4 = (const float4*)echiS;
  for (int base = beg; base < end; base += EC) {
    int m = min(EC, end - base);
    __syncthreads();
    for (int idx = t; idx < m*(FW/4); idx += 256)
      ((float4*)s_e)[idx] = f4[(size_t)base*(FW/4) + idx];
    for (int idx = t; idx < m*3; idx += 256)
      ((float4*)s_ec)[idx] = e4[(size_t)base*3 + idx];
    __syncthreads();
    int p = 0;
    for (; p + 3 < m; p += 4) {
      int sd0 = sndS[base+p+0], sd1 = sndS[base+p+1];
      int sd2 = sndS[base+p+2], sd3 = sndS[base+p+3];
      __half2 g0a = A1h2[(size_t)sd0*NP2 + qg[0]];
      __half2 g1a = A1h2[(size_t)sd1*NP2 + qg[0]];
      __half2 g2a = A1h2[(size_t)sd2*NP2 + qg[0]];
      __half2 g3a = A1h2[(size_t)sd3*NP2 + qg[0]];
      __half2 g0b, g1b, g2b, g3b;
      if (val[1]) {
        g0b = A1h2[(size_t)sd0*NP2 + qg[1]];
        g1b = A1h2[(size_t)sd1*NP2 + qg[1]];
        g2b = A1h2[(size_t)sd2*NP2 + qg[1]];
        g3b = A1h2[(size_t)sd3*NP2 + qg[1]];
      }
      #pragma unroll
      for (int x = 0; x < 4; ++x) {
        const float* e0 = s_e + (p+x)*FW;
        const float* x0 = s_ec + (p+x)*12;
        __half2 ga = (x==0)?g0a:(x==1)?g1a:(x==2)?g2a:g3a;
        {
          float rv = e0[rq[0]];
          float2 gf = __half22float2(ga);
          accA[0][0] += gf.x * rv;
          accA[0][1] += gf.y * rv;
          accB[0][0] += rv * e0[8+i0[0]] * x0[c0[0]];
          accB[0][1] += rv * e0[8+i1[0]] * x0[c1[0]];
        }
        if (val[1]) {
          __half2 gb = (x==0)?g0b:(x==1)?g1b:(x==2)?g2b:g3b;
          float rv = e0[rq[1]];
          float2 gf = __half22float2(gb);
          accA[1][0] += gf.x * rv;
          accA[1][1] += gf.y * rv;
          accB[1][0] += rv * e0[8+i0[1]] * x0[c0[1]];
          accB[1][1] += rv * e0[8+i1[1]] * x0[c1[1]];
        }
      }
    }
    for (; p < m; ++p) {
      int sd = sndS[base+p];
      const float* e0 = s_e + p*FW;
      const float* x0 = s_ec + p*12;
      const __half2* Ah = A1h2 + (size_t)sd*NP2;
      #pragma unroll
      for (int jj = 0; jj < 2; ++jj) {
        if (val[jj]) {
          float rv = e0[rq[jj]];
          float2 gf = __half22float2(Ah[qg[jj]]);
          accA[jj][0] += gf.x * rv;
          accA[jj][1] += gf.y * rv;
          accB[jj][0] += rv * e0[8+i0[jj]] * x0[c0[jj]];
          accB[jj][1] += rv * e0[8+i1[jj]] * x0[c1[jj]];
        }
      }
    }
  }
  __syncthreads();
  #pragma unroll
  for (int jj = 0; jj < 2; ++jj)
    if (val[jj]) {
      s_tile[rq[jj]*90 + 2*kk[jj]]     = accB[jj][0];
      s_tile[rq[jj]*90 + 2*kk[jj] + 1] = accB[jj][1];
    }
  __syncthreads();
  float a2v[2][2];
  #pragma unroll
  for (int jj = 0; jj < 2; ++jj) {
    if (val[jj]) {
      float ab0 = 0.f, ab1 = 0.f;
      #pragma unroll
      for (int r = 0; r < NRB; ++r) {
        ab0 += s_tile[r*90 + 2*kk[jj]]     * s_wrt[l0[jj]*64 + r*8 + rq[jj]];
        ab1 += s_tile[r*90 + 2*kk[jj] + 1] * s_wrt[l1[jj]*64 + r*8 + rq[jj]];
      }
      float mem0 = mymem[jj].x * s_wnm[rq[jj]*36 + l0[jj]*9 + c0[jj]];
      float mem1 = mymem[jj].y * s_wnm[rq[jj]*36 + l1[jj]*9 + c1[jj]];
      a2v[jj][0] = (ab0 + accA[jj][0])*MPN + mem0;
      a2v[jj][1] = (ab1 + accA[jj][1])*MPN + mem1;
    }
  }
  __syncthreads();
  #pragma unroll
  for (int jj = 0; jj < 2; ++jj)
    if (val[jj]) {
      s_tile[rq[jj]*90 + 2*kk[jj]]     = a2v[jj][0];
      s_tile[rq[jj]*90 + 2*kk[jj] + 1] = a2v[jj][1];
    }
  __syncthreads();
  if (half == 0) {
    for (int m2 = t; m2 < 288; m2 += 256) {
      int s = m2 / 36, rm = m2 % 36, l5 = rm / 9, c = rm % 9;
      float b;
      if (l5 == 0) b = s_tile[s*90 + c];
      else {
        b = 0.f;
        for (int i = c_GB[l5]; i < c_GE[l5]; ++i) {
          float v = s_tile[s*90 + i*9 + c];
          b += c_PREF[i]*v*v;
        }
      }
      out[(size_t)(((n*8 + s)*5 + l5)*9 + c)*2 + 1] = b;
    }
  } else {
    if (t < 72) {
      int s = t / 9, c = t % 9;
      float b = 0.f;
      for (int i = 10; i < 20; ++i) {
        float v = s_tile[s*90 + (i-10)*9 + c];
        b += c_PREF[i]*v*v;
      }
      out[(size_t)(((n*8 + s)*5 + 4)*9 + c)*2 + 1] = b;
    }
  }
}

extern "C" void kernel_launch(void* const* d_in, const int* in_sizes, int n_in,
                              void* d_out, int out_size, void* d_ws, size_t ws_size,
                              hipStream_t stream) {
  const float* pos    = (const float*)d_in[0];
  const float* shifts = (const float*)d_in[1];
  const float* W_emb  = (const float*)d_in[2];
  const float* W_rt   = (const float*)d_in[3];
  const float* W_nm   = (const float*)d_in[4];
  const int*   an     = (const int*)d_in[5];
  const int*   ei     = (const int*)d_in[6];
  float* out = (float*)d_out;

  char* ws = (char*)d_ws;
  size_t off = 0;
  auto carve = [&](size_t bytes) {
    void* p = ws + off;
    off = (off + bytes + 255) & ~(size_t)255;
    return p;
  };
  float*   facS    = (float*)carve((size_t)FW*NEDGE*sizeof(float));
  int*     sndS    = (int*)carve((size_t)NEDGE*sizeof(int));
  float*   echiS   = (float*)carve((size_t)12*NEDGE*sizeof(float));
  float2*  A1f2    = (float2*)carve((size_t)NNODE*NEL*sizeof(float));
  __half2* A1h2    = (__half2*)carve((size_t)NNODE*NEL*sizeof(__half));
  float*   chi     = (float*)carve((size_t)NNODE*NCH*sizeof(float));
  int*     counts  = (int*)carve((size_t)NNODE*sizeof(int));
  int*     offsets = (int*)carve((size_t)(NNODE+1)*sizeof(int));
  int*     cursor  = (int*)carve((size_t)NNODE*sizeof(int));

  // one memset covers chi..counts (adjacent carves)
  size_t z0 = (size_t)((char*)chi - ws);
  size_t z1 = (size_t)((char*)counts - ws) + (size_t)NNODE*sizeof(int);
  hipMemsetAsync((char*)ws + z0, 0, z1 - z0, stream);
  k_count<<<(NEDGE+255)/256, 256, 0, stream>>>(ei, counts);
  k_scan<<<1, 1024, 0, stream>>>(counts, offsets, cursor);
  k_edgec<<<(NEDGE+255)/256, 256, 0, stream>>>(pos, shifts, ei, an, W_emb, cursor, facS, sndS);
  k_nodeA<<<NNODE*2, 256, 0, stream>>>(facS, offsets, W_rt, A1f2, A1h2, chi, out);
  k_echi<<<(NEDGE+255)/256, 256, 0, stream>>>(facS, sndS, chi, echiS);
  k_nodeMP<<<NNODE*2, 256, 0, stream>>>(facS, offsets, sndS, echiS, W_rt, W_nm, A1f2, A1h2, out);
}